// Round 1
// baseline (619.783 us; speedup 1.0000x reference)
//
#include <hip/hip_runtime.h>

#define EDIM 1024
#define LSEQ 2048
#define NBATCH 2
#define NHEADS 16
#define HDIM 64
#define NBH 32   // NBATCH*NHEADS

typedef __attribute__((ext_vector_type(8))) short short8;
typedef __attribute__((ext_vector_type(4))) float floatx4;

#define MFMA16(a, b, c) __builtin_amdgcn_mfma_f32_16x16x32_bf16((a), (b), (c), 0, 0, 0)

__device__ __forceinline__ unsigned short f2bf(float f) {
  unsigned int u = __float_as_uint(f);
  u += 0x7fffu + ((u >> 16) & 1u);
  return (unsigned short)(u >> 16);
}

// ---------------- fp32 -> bf16 bulk convert (8 elems / thread) ----------------
__global__ void k_f2bf(const float* __restrict__ src, unsigned short* __restrict__ dst, int n8) {
  int i = blockIdx.x * blockDim.x + threadIdx.x;
  int stride = gridDim.x * blockDim.x;
  for (; i < n8; i += stride) {
    float4 a = ((const float4*)src)[2 * i];
    float4 b = ((const float4*)src)[2 * i + 1];
    union { unsigned short u[8]; uint4 v; } o;
    o.u[0] = f2bf(a.x); o.u[1] = f2bf(a.y); o.u[2] = f2bf(a.z); o.u[3] = f2bf(a.w);
    o.u[4] = f2bf(b.x); o.u[5] = f2bf(b.y); o.u[6] = f2bf(b.z); o.u[7] = f2bf(b.w);
    ((uint4*)dst)[i] = o.v;
  }
}

// ---------------- GEMM: C[M=4096][1024] = A[4096][1024] @ W[1024][1024]^T + bias ----------------
// MODE 0: write bf16 scattered to [bh][seq][64]   (q, k projections)
// MODE 1: write bf16 scattered to Vt [bh][64][seq] (v projection, transposed)
// MODE 2: write fp32 directly to out[row][col]     (final projection)
template <int MODE>
__global__ __launch_bounds__(256) void k_gemm(const unsigned short* __restrict__ A,
                                              const unsigned short* __restrict__ B,
                                              const float* __restrict__ bias,
                                              void* __restrict__ outp) {
  __shared__ unsigned short As[128 * 32];
  __shared__ unsigned short Bs[128 * 32];
  const int row0 = blockIdx.x * 128;
  const int col0 = blockIdx.y * 128;
  const int t = threadIdx.x;
  const int w = t >> 6, lane = t & 63;
  const int g = lane >> 4, lr = lane & 15;
  const int wm = (w >> 1) * 64, wn = (w & 1) * 64;
  const int r = t >> 2, c8 = (t & 3) * 8;

  floatx4 acc[4][4];
#pragma unroll
  for (int mi = 0; mi < 4; ++mi)
#pragma unroll
    for (int ni = 0; ni < 4; ++ni) acc[mi][ni] = (floatx4){0.f, 0.f, 0.f, 0.f};

  for (int k0 = 0; k0 < 1024; k0 += 32) {
#pragma unroll
    for (int i = 0; i < 2; ++i) {
      *(uint4*)&As[(i * 64 + r) * 32 + c8] = *(const uint4*)&A[(row0 + i * 64 + r) * 1024 + k0 + c8];
      *(uint4*)&Bs[(i * 64 + r) * 32 + c8] = *(const uint4*)&B[(col0 + i * 64 + r) * 1024 + k0 + c8];
    }
    __syncthreads();
    short8 af[4], bf[4];
#pragma unroll
    for (int mi = 0; mi < 4; ++mi) af[mi] = *(const short8*)&As[(wm + mi * 16 + lr) * 32 + g * 8];
#pragma unroll
    for (int ni = 0; ni < 4; ++ni) bf[ni] = *(const short8*)&Bs[(wn + ni * 16 + lr) * 32 + g * 8];
#pragma unroll
    for (int mi = 0; mi < 4; ++mi)
#pragma unroll
      for (int ni = 0; ni < 4; ++ni) acc[mi][ni] = MFMA16(af[mi], bf[ni], acc[mi][ni]);
    __syncthreads();
  }

#pragma unroll
  for (int ni = 0; ni < 4; ++ni) {
    const int col = col0 + wn + ni * 16 + lr;
    const float bv = bias[col];
#pragma unroll
    for (int mi = 0; mi < 4; ++mi) {
#pragma unroll
      for (int i = 0; i < 4; ++i) {
        const int row = row0 + wm + mi * 16 + g * 4 + i;
        const float v = acc[mi][ni][i] + bv;
        if (MODE == 2) {
          ((float*)outp)[row * 1024 + col] = v;
        } else {
          const int n = row & 1, sq = row >> 1;
          const int h = col >> 6, d = col & 63;
          if (MODE == 0)
            ((unsigned short*)outp)[((n * NHEADS + h) * LSEQ + sq) * HDIM + d] = f2bf(v);
          else
            ((unsigned short*)outp)[((n * NHEADS + h) * HDIM + d) * LSEQ + sq] = f2bf(v);
        }
      }
    }
  }
}

// ---------------- pass 1: ell[bh][l] = sum_s exp(q.k/8)  (no-max softmax denom) ----------------
__global__ __launch_bounds__(256) void k_stats(const unsigned short* __restrict__ qb,
                                               const unsigned short* __restrict__ kb,
                                               float* __restrict__ ell) {
  const int bh = blockIdx.x;
  const int l0 = blockIdx.y * 64;
  const int t = threadIdx.x, w = t >> 6, lane = t & 63;
  const int g = lane >> 4, lr = lane & 15;
  const int lrow = l0 + w * 16;
  const unsigned short* qrow = qb + (bh * LSEQ + lrow + lr) * HDIM;
  const short8 q0 = *(const short8*)(qrow + g * 8);
  const short8 q1 = *(const short8*)(qrow + 32 + g * 8);
  float s_run[4] = {0.f, 0.f, 0.f, 0.f};
  for (int s0 = 0; s0 < LSEQ; s0 += 64) {
    floatx4 acc[4];
#pragma unroll
    for (int ni = 0; ni < 4; ++ni) {
      const unsigned short* krow = kb + (bh * LSEQ + s0 + ni * 16 + lr) * HDIM;
      const short8 k0 = *(const short8*)(krow + g * 8);
      const short8 k1 = *(const short8*)(krow + 32 + g * 8);
      floatx4 a = (floatx4){0.f, 0.f, 0.f, 0.f};
      a = MFMA16(q0, k0, a);
      a = MFMA16(q1, k1, a);
      acc[ni] = a;
    }
#pragma unroll
    for (int ni = 0; ni < 4; ++ni)
#pragma unroll
      for (int i = 0; i < 4; ++i) s_run[i] += __expf(acc[ni][i] * 0.125f);
  }
#pragma unroll
  for (int i = 0; i < 4; ++i) {
    float v = s_run[i];
    v += __shfl_xor(v, 1);
    v += __shfl_xor(v, 2);
    v += __shfl_xor(v, 4);
    v += __shfl_xor(v, 8);
    if (lr == 0) ell[bh * LSEQ + lrow + g * 4 + i] = v;
  }
}

// ---------------- pass 2: O[(l,n),(h,d)] = (P~ @ V) / ell ----------------
__global__ __launch_bounds__(256) void k_pv(const unsigned short* __restrict__ qb,
                                            const unsigned short* __restrict__ kb,
                                            const unsigned short* __restrict__ vt,
                                            const float* __restrict__ ell,
                                            unsigned short* __restrict__ O) {
  __shared__ unsigned short P[4][16 * 32];
  const int bh = blockIdx.x;
  const int l0 = blockIdx.y * 64;
  const int t = threadIdx.x, w = t >> 6, lane = t & 63;
  const int g = lane >> 4, lr = lane & 15;
  const int lrow = l0 + w * 16;
  const unsigned short* qrow = qb + (bh * LSEQ + lrow + lr) * HDIM;
  const short8 q0 = *(const short8*)(qrow + g * 8);
  const short8 q1 = *(const short8*)(qrow + 32 + g * 8);
  unsigned short* Pw = P[w];
  floatx4 oacc[4];
#pragma unroll
  for (int ni = 0; ni < 4; ++ni) oacc[ni] = (floatx4){0.f, 0.f, 0.f, 0.f};

  for (int s0 = 0; s0 < LSEQ; s0 += 32) {
    floatx4 sa[2];
#pragma unroll
    for (int sub = 0; sub < 2; ++sub) {
      const unsigned short* krow = kb + (bh * LSEQ + s0 + sub * 16 + lr) * HDIM;
      const short8 k0 = *(const short8*)(krow + g * 8);
      const short8 k1 = *(const short8*)(krow + 32 + g * 8);
      floatx4 a = (floatx4){0.f, 0.f, 0.f, 0.f};
      a = MFMA16(q0, k0, a);
      a = MFMA16(q1, k1, a);
      sa[sub] = a;
    }
#pragma unroll
    for (int sub = 0; sub < 2; ++sub)
#pragma unroll
      for (int i = 0; i < 4; ++i)
        Pw[(g * 4 + i) * 32 + sub * 16 + lr] = f2bf(__expf(sa[sub][i] * 0.125f));
    const short8 pf = *(const short8*)&Pw[lr * 32 + g * 8];
#pragma unroll
    for (int ni = 0; ni < 4; ++ni) {
      const short8 vf = *(const short8*)&vt[(bh * HDIM + ni * 16 + lr) * LSEQ + s0 + g * 8];
      oacc[ni] = MFMA16(pf, vf, oacc[ni]);
    }
  }

  const int n = bh >> 4, h = bh & 15;
#pragma unroll
  for (int i = 0; i < 4; ++i) {
    const int l = lrow + g * 4 + i;
    const float rl = 1.0f / ell[bh * LSEQ + l];
#pragma unroll
    for (int ni = 0; ni < 4; ++ni)
      O[(l * NBATCH + n) * EDIM + h * HDIM + ni * 16 + lr] = f2bf(oacc[ni][i] * rl);
  }
}

// ---------------- weights: W[n][l][s] = mean_h exp(q.k/8)/ell ----------------
__global__ __launch_bounds__(256) void k_weights(const unsigned short* __restrict__ qb,
                                                 const unsigned short* __restrict__ kb,
                                                 const float* __restrict__ ell,
                                                 float* __restrict__ Wout) {
  const int l0 = blockIdx.x * 64;
  const int s0 = blockIdx.y * 64;
  const int n = blockIdx.z;
  const int t = threadIdx.x, w = t >> 6, lane = t & 63;
  const int g = lane >> 4, lr = lane & 15;
  const int lrow = l0 + w * 16;
  float wacc[4][4];
#pragma unroll
  for (int ni = 0; ni < 4; ++ni)
#pragma unroll
    for (int i = 0; i < 4; ++i) wacc[ni][i] = 0.f;

  for (int h = 0; h < NHEADS; ++h) {
    const int bh = n * NHEADS + h;
    const unsigned short* qrow = qb + (bh * LSEQ + lrow + lr) * HDIM;
    const short8 q0 = *(const short8*)(qrow + g * 8);
    const short8 q1 = *(const short8*)(qrow + 32 + g * 8);
    float rl[4];
#pragma unroll
    for (int i = 0; i < 4; ++i) rl[i] = 1.0f / ell[bh * LSEQ + lrow + g * 4 + i];
#pragma unroll
    for (int ni = 0; ni < 4; ++ni) {
      const unsigned short* krow = kb + (bh * LSEQ + s0 + ni * 16 + lr) * HDIM;
      const short8 k0 = *(const short8*)(krow + g * 8);
      const short8 k1 = *(const short8*)(krow + 32 + g * 8);
      floatx4 a = (floatx4){0.f, 0.f, 0.f, 0.f};
      a = MFMA16(q0, k0, a);
      a = MFMA16(q1, k1, a);
#pragma unroll
      for (int i = 0; i < 4; ++i) wacc[ni][i] += __expf(a[i] * 0.125f) * rl[i];
    }
  }
#pragma unroll
  for (int ni = 0; ni < 4; ++ni)
#pragma unroll
    for (int i = 0; i < 4; ++i)
      Wout[(n * LSEQ + lrow + g * 4 + i) * LSEQ + s0 + ni * 16 + lr] = wacc[ni][i] * 0.0625f;
}

extern "C" void kernel_launch(void* const* d_in, const int* in_sizes, int n_in,
                              void* d_out, int out_size, void* d_ws, size_t ws_size,
                              hipStream_t stream) {
  const float* query = (const float*)d_in[0];
  const float* key   = (const float*)d_in[1];
  const float* value = (const float*)d_in[2];
  const float* Wq = (const float*)d_in[3]; const float* bq = (const float*)d_in[4];
  const float* Wk = (const float*)d_in[5]; const float* bk = (const float*)d_in[6];
  const float* Wv = (const float*)d_in[7]; const float* bv = (const float*)d_in[8];
  const float* Wo = (const float*)d_in[9]; const float* bo = (const float*)d_in[10];

  const size_t MB = 1u << 20;
  char* ws = (char*)d_ws;
  unsigned short* Xq  = (unsigned short*)(ws + 0 * MB);
  unsigned short* Xk  = (unsigned short*)(ws + 8 * MB);
  unsigned short* Xv  = (unsigned short*)(ws + 16 * MB);
  unsigned short* Wqb = (unsigned short*)(ws + 24 * MB);
  unsigned short* Wkb = (unsigned short*)(ws + 26 * MB);
  unsigned short* Wvb = (unsigned short*)(ws + 28 * MB);
  unsigned short* Wob = (unsigned short*)(ws + 30 * MB);
  unsigned short* qbuf = (unsigned short*)(ws + 32 * MB);
  unsigned short* kbuf = (unsigned short*)(ws + 40 * MB);
  unsigned short* Vt   = (unsigned short*)(ws + 48 * MB);
  unsigned short* Obuf = (unsigned short*)(ws + 56 * MB);
  float* ell = (float*)(ws + 64 * MB);

  // convert inputs to bf16
  k_f2bf<<<dim3(1024), 256, 0, stream>>>(query, Xq, 4096 * 1024 / 8);
  k_f2bf<<<dim3(1024), 256, 0, stream>>>(key,   Xk, 4096 * 1024 / 8);
  k_f2bf<<<dim3(1024), 256, 0, stream>>>(value, Xv, 4096 * 1024 / 8);
  k_f2bf<<<dim3(256), 256, 0, stream>>>(Wq, Wqb, 1024 * 1024 / 8);
  k_f2bf<<<dim3(256), 256, 0, stream>>>(Wk, Wkb, 1024 * 1024 / 8);
  k_f2bf<<<dim3(256), 256, 0, stream>>>(Wv, Wvb, 1024 * 1024 / 8);
  k_f2bf<<<dim3(256), 256, 0, stream>>>(Wo, Wob, 1024 * 1024 / 8);

  // projections
  dim3 gg(32, 8);
  k_gemm<0><<<gg, 256, 0, stream>>>(Xq, Wqb, bq, qbuf);
  k_gemm<0><<<gg, 256, 0, stream>>>(Xk, Wkb, bk, kbuf);
  k_gemm<1><<<gg, 256, 0, stream>>>(Xv, Wvb, bv, Vt);

  // attention
  k_stats<<<dim3(32, 32), 256, 0, stream>>>(qbuf, kbuf, ell);
  k_pv<<<dim3(32, 32), 256, 0, stream>>>(qbuf, kbuf, Vt, ell, Obuf);

  // output projection (fp32 direct to d_out) + head-averaged weights
  k_gemm<2><<<gg, 256, 0, stream>>>(Obuf, Wob, bo, d_out);
  k_weights<<<dim3(32, 32, 2), 256, 0, stream>>>(qbuf, kbuf, ell, (float*)d_out + 4194304);
}

// Round 2
// 217.713 us; speedup vs baseline: 2.8468x; 2.8468x over previous
//
#include <hip/hip_runtime.h>

#define EDIM 1024
#define LSEQ 2048
#define NBATCH 2
#define NHEADS 16
#define HDIM 64

typedef unsigned short us;
typedef __attribute__((ext_vector_type(8))) short short8;
typedef __attribute__((ext_vector_type(4))) float floatx4;

#define MFMA16(a, b, c) __builtin_amdgcn_mfma_f32_16x16x32_bf16((a), (b), (c), 0, 0, 0)

__device__ __forceinline__ us f2bf(float f) {
  unsigned int u = __float_as_uint(f);
  u += 0x7fffu + ((u >> 16) & 1u);
  return (us)(u >> 16);
}

// async global -> LDS, 16B per lane; dst is wave-uniform base, lanes write base + lane*16
__device__ __forceinline__ void gload16(const void* g, void* l) {
  __builtin_amdgcn_global_load_lds((const __attribute__((address_space(1))) unsigned int*)g,
                                   (__attribute__((address_space(3))) unsigned int*)l, 16, 0, 0);
}

// ---------------- fp32 -> bf16 bulk convert (8 elems / thread) ----------------
__global__ void k_f2bf(const float* __restrict__ src, us* __restrict__ dst, int n8) {
  int i = blockIdx.x * blockDim.x + threadIdx.x;
  int stride = gridDim.x * blockDim.x;
  for (; i < n8; i += stride) {
    float4 a = ((const float4*)src)[2 * i];
    float4 b = ((const float4*)src)[2 * i + 1];
    union { us u[8]; uint4 v; } o;
    o.u[0] = f2bf(a.x); o.u[1] = f2bf(a.y); o.u[2] = f2bf(a.z); o.u[3] = f2bf(a.w);
    o.u[4] = f2bf(b.x); o.u[5] = f2bf(b.y); o.u[6] = f2bf(b.z); o.u[7] = f2bf(b.w);
    ((uint4*)dst)[i] = o.v;
  }
}

// ---------------- GEMM core: C[64 x 128] tile of A[4096][1024] @ W[1024][1024]^T + bias ----
// MODE 0: bf16 scatter [bh][seq][64]; MODE 1: bf16 scatter Vt [bh][64][seq]; MODE 2: fp32 direct
template <int MODE>
__device__ __forceinline__ void gemm_core(us* As, us* Bs,
                                          const us* __restrict__ A, const us* __restrict__ B,
                                          const float* __restrict__ bias, void* __restrict__ outp,
                                          int row0, int col0) {
  const int t = threadIdx.x;
  const int w = t >> 6, lane = t & 63;
  const int g = lane >> 4, lr = lane & 15;
  const int wm = (w & 1) * 32, wn = (w >> 1) * 64;
  const int srow = lane >> 2, sc = (lane & 3) * 8;  // 1KB chunk = 16 rows x 64B
  const us* Asrc = A + (size_t)(row0 + w * 16 + srow) * EDIM + sc;
  const us* Bsrc0 = B + (size_t)(col0 + w * 32 + srow) * EDIM + sc;
  const us* Bsrc1 = Bsrc0 + 16 * EDIM;

  floatx4 acc[2][4];
#pragma unroll
  for (int mi = 0; mi < 2; ++mi)
#pragma unroll
    for (int ni = 0; ni < 4; ++ni) acc[mi][ni] = (floatx4){0.f, 0.f, 0.f, 0.f};

  for (int k0 = 0; k0 < EDIM; k0 += 32) {
    gload16(Asrc + k0, As + w * 512);
    gload16(Bsrc0 + k0, Bs + w * 1024);
    gload16(Bsrc1 + k0, Bs + w * 1024 + 512);
    __syncthreads();
    short8 af[2], bfr[4];
#pragma unroll
    for (int mi = 0; mi < 2; ++mi) af[mi] = *(const short8*)&As[(wm + mi * 16 + lr) * 32 + g * 8];
#pragma unroll
    for (int ni = 0; ni < 4; ++ni) bfr[ni] = *(const short8*)&Bs[(wn + ni * 16 + lr) * 32 + g * 8];
#pragma unroll
    for (int mi = 0; mi < 2; ++mi)
#pragma unroll
      for (int ni = 0; ni < 4; ++ni) acc[mi][ni] = MFMA16(af[mi], bfr[ni], acc[mi][ni]);
    __syncthreads();
  }

#pragma unroll
  for (int ni = 0; ni < 4; ++ni) {
    const int col = col0 + wn + ni * 16 + lr;
    const float bv = bias[col];
#pragma unroll
    for (int mi = 0; mi < 2; ++mi) {
#pragma unroll
      for (int i = 0; i < 4; ++i) {
        const int row = row0 + wm + mi * 16 + g * 4 + i;
        const float v = acc[mi][ni][i] + bv;
        if (MODE == 2) {
          ((float*)outp)[(size_t)row * EDIM + col] = v;
        } else {
          const int n = row & 1, sq = row >> 1;
          const int h = col >> 6, d = col & 63;
          if (MODE == 0)
            ((us*)outp)[(((size_t)n * NHEADS + h) * LSEQ + sq) * HDIM + d] = f2bf(v);
          else
            ((us*)outp)[(((size_t)n * NHEADS + h) * HDIM + d) * LSEQ + sq] = f2bf(v);
        }
      }
    }
  }
}

__global__ __launch_bounds__(256) void k_gemm_qkv(
    const us* __restrict__ Xq, const us* __restrict__ Xk, const us* __restrict__ Xv,
    const us* __restrict__ Wqb, const us* __restrict__ Wkb, const us* __restrict__ Wvb,
    const float* __restrict__ bq, const float* __restrict__ bk, const float* __restrict__ bv,
    us* __restrict__ qo, us* __restrict__ ko, us* __restrict__ vo) {
  __shared__ us As[64 * 32];
  __shared__ us Bs[128 * 32];
  const int z = blockIdx.z;
  const us* A = (z == 0) ? Xq : (z == 1) ? Xk : Xv;
  const us* B = (z == 0) ? Wqb : (z == 1) ? Wkb : Wvb;
  const float* bias = (z == 0) ? bq : (z == 1) ? bk : bv;
  void* o = (z == 0) ? (void*)qo : (z == 1) ? (void*)ko : (void*)vo;
  if (z < 2) gemm_core<0>(As, Bs, A, B, bias, o, blockIdx.x * 64, blockIdx.y * 128);
  else       gemm_core<1>(As, Bs, A, B, bias, o, blockIdx.x * 64, blockIdx.y * 128);
}

__global__ __launch_bounds__(256) void k_gemm_o(const us* __restrict__ A, const us* __restrict__ B,
                                                const float* __restrict__ bias, float* __restrict__ out) {
  __shared__ us As[64 * 32];
  __shared__ us Bs[128 * 32];
  gemm_core<2>(As, Bs, A, B, bias, out, blockIdx.x * 64, blockIdx.y * 128);
}

// ---------------- fused attention: O = softmax(QK^T/8) V, also writes ell ----------------
// grid (bh=32, lblk=32), 256 thr. K/V tiles (64x64) double-buffered in LDS, XOR-swizzled.
__global__ __launch_bounds__(256) void k_attn(const us* __restrict__ qb, const us* __restrict__ kb,
                                              const us* __restrict__ vt, float* __restrict__ ell,
                                              us* __restrict__ O) {
  __shared__ us Ks[2][64 * 64];
  __shared__ us Vs[2][64 * 64];
  __shared__ us Ps[4][16 * 64];
  const int bh = blockIdx.x;
  const int l0 = blockIdx.y * 64;
  const int t = threadIdx.x, w = t >> 6, lane = t & 63;
  const int g = lane >> 4, lr = lane & 15;
  const int lrow = l0 + w * 16;

  // Q fragments (A operand, rows = lr)
  const us* qrow = qb + ((size_t)bh * LSEQ + lrow + lr) * HDIM;
  const short8 q0 = *(const short8*)(qrow + g * 8);
  const short8 q1 = *(const short8*)(qrow + 32 + g * 8);

  // staging: chunk j covers tile rows j*8..j*8+7; lane l -> row j*8+(l>>3),
  // source col pre-swizzled: elem ((l&7)^(l>>3))*8  (inverse of read-side XOR)
  const int j0 = w * 2, j1 = w * 2 + 1;
  const int srA = lane >> 3;
  const int scA = ((lane & 7) ^ (lane >> 3)) * 8;
  const us* Kbase = kb + (size_t)bh * LSEQ * HDIM;
  const us* Vbase = vt + (size_t)bh * HDIM * LSEQ;
  const us* Ksrc0 = Kbase + (j0 * 8 + srA) * HDIM + scA;
  const us* Ksrc1 = Kbase + (j1 * 8 + srA) * HDIM + scA;
  const us* Vsrc0 = Vbase + (size_t)(j0 * 8 + srA) * LSEQ + scA;
  const us* Vsrc1 = Vbase + (size_t)(j1 * 8 + srA) * LSEQ + scA;

  us* Pw = Ps[w];
  const int swz = (lr & 7) << 3;  // read-side XOR (elem units)

  floatx4 oacc[4];
#pragma unroll
  for (int ni = 0; ni < 4; ++ni) oacc[ni] = (floatx4){0.f, 0.f, 0.f, 0.f};
  float ellacc[4] = {0.f, 0.f, 0.f, 0.f};

  // prologue: stage tile 0
  gload16(Ksrc0, &Ks[0][j0 * 512]); gload16(Ksrc1, &Ks[0][j1 * 512]);
  gload16(Vsrc0, &Vs[0][j0 * 512]); gload16(Vsrc1, &Vs[0][j1 * 512]);
  __syncthreads();

  for (int it = 0; it < 32; ++it) {
    const int cur = it & 1;
    if (it < 31) {
      const int so = (it + 1) * 64;
      us* Kn = Ks[cur ^ 1]; us* Vn = Vs[cur ^ 1];
      gload16(Ksrc0 + so * HDIM, Kn + j0 * 512);
      gload16(Ksrc1 + so * HDIM, Kn + j1 * 512);
      gload16(Vsrc0 + so, Vn + j0 * 512);
      gload16(Vsrc1 + so, Vn + j1 * 512);
    }
    const us* Kc = Ks[cur];
    const us* Vc = Vs[cur];

    // QK^T: S tile 16 x 64 per wave
    floatx4 sacc[4];
#pragma unroll
    for (int ni = 0; ni < 4; ++ni) {
      const int rb = (ni * 16 + lr) * 64;
      const short8 kf0 = *(const short8*)&Kc[rb + ((g * 8) ^ swz)];
      const short8 kf1 = *(const short8*)&Kc[rb + ((32 + g * 8) ^ swz)];
      floatx4 a = (floatx4){0.f, 0.f, 0.f, 0.f};
      a = MFMA16(q0, kf0, a);
      a = MFMA16(q1, kf1, a);
      sacc[ni] = a;
    }
    // exp, ell accumulate, P -> LDS (swizzled per-row)
#pragma unroll
    for (int i = 0; i < 4; ++i) {
      const int r = g * 4 + i;
      const int rx = (r & 7) << 3;
#pragma unroll
      for (int ni = 0; ni < 4; ++ni) {
        const float e = __expf(sacc[ni][i] * 0.125f);
        ellacc[i] += e;
        Pw[r * 64 + ((ni * 16 + lr) ^ rx)] = f2bf(e);
      }
    }
    // PV: A = P (rows lr), B = Vt (cols = d)
    const short8 pf0 = *(const short8*)&Pw[lr * 64 + ((g * 8) ^ swz)];
    const short8 pf1 = *(const short8*)&Pw[lr * 64 + ((32 + g * 8) ^ swz)];
#pragma unroll
    for (int ni = 0; ni < 4; ++ni) {
      const int rb = (ni * 16 + lr) * 64;
      const short8 vf0 = *(const short8*)&Vc[rb + ((g * 8) ^ swz)];
      const short8 vf1 = *(const short8*)&Vc[rb + ((32 + g * 8) ^ swz)];
      oacc[ni] = MFMA16(pf0, vf0, oacc[ni]);
      oacc[ni] = MFMA16(pf1, vf1, oacc[ni]);
    }
    __syncthreads();
  }

  // ell: butterfly sum over the 16 lr-lanes (all lanes end with row sum)
#pragma unroll
  for (int i = 0; i < 4; ++i) {
    float v = ellacc[i];
    v += __shfl_xor(v, 1);
    v += __shfl_xor(v, 2);
    v += __shfl_xor(v, 4);
    v += __shfl_xor(v, 8);
    ellacc[i] = v;
  }
  if (lr == 0) {
#pragma unroll
    for (int i = 0; i < 4; ++i) ell[bh * LSEQ + lrow + g * 4 + i] = ellacc[i];
  }

  const int n = bh >> 4, h = bh & 15;
#pragma unroll
  for (int i = 0; i < 4; ++i) {
    const int l = lrow + g * 4 + i;
    const float rl = 1.0f / ellacc[i];
#pragma unroll
    for (int ni = 0; ni < 4; ++ni)
      O[((size_t)l * NBATCH + n) * EDIM + h * HDIM + ni * 16 + lr] = f2bf(oacc[ni][i] * rl);
  }
}

// ---------------- weights: W[n][l][s] = mean_h exp(q.k/8)/ell ----------------
// grid (lblk=32, sblk=32, n=2). K tile staged in LDS per head, double-buffered.
__global__ __launch_bounds__(256) void k_weights(const us* __restrict__ qb, const us* __restrict__ kb,
                                                 const float* __restrict__ ell, float* __restrict__ Wout) {
  __shared__ us Ks[2][64 * 64];
  const int l0 = blockIdx.x * 64;
  const int s0 = blockIdx.y * 64;
  const int n = blockIdx.z;
  const int t = threadIdx.x, w = t >> 6, lane = t & 63;
  const int g = lane >> 4, lr = lane & 15;
  const int lrow = l0 + w * 16;
  const int j0 = w * 2, j1 = w * 2 + 1;
  const int srA = lane >> 3;
  const int scA = ((lane & 7) ^ (lane >> 3)) * 8;
  const us* Kb0 = kb + ((size_t)(n * NHEADS) * LSEQ + s0 + j0 * 8 + srA) * HDIM + scA;
  const us* Kb1 = kb + ((size_t)(n * NHEADS) * LSEQ + s0 + j1 * 8 + srA) * HDIM + scA;
  const int swz = (lr & 7) << 3;

  float wacc[4][4];
#pragma unroll
  for (int ni = 0; ni < 4; ++ni)
#pragma unroll
    for (int i = 0; i < 4; ++i) wacc[ni][i] = 0.f;

  gload16(Kb0, &Ks[0][j0 * 512]); gload16(Kb1, &Ks[0][j1 * 512]);
  __syncthreads();

  for (int h = 0; h < NHEADS; ++h) {
    const int cur = h & 1;
    if (h < NHEADS - 1) {
      us* Kn = Ks[cur ^ 1];
      gload16(Kb0 + (size_t)(h + 1) * LSEQ * HDIM, Kn + j0 * 512);
      gload16(Kb1 + (size_t)(h + 1) * LSEQ * HDIM, Kn + j1 * 512);
    }
    const int bh = n * NHEADS + h;
    const us* qrow = qb + ((size_t)bh * LSEQ + lrow + lr) * HDIM;
    const short8 q0 = *(const short8*)(qrow + g * 8);
    const short8 q1 = *(const short8*)(qrow + 32 + g * 8);
    float rl[4];
#pragma unroll
    for (int i = 0; i < 4; ++i) rl[i] = 1.0f / ell[bh * LSEQ + lrow + g * 4 + i];
    const us* Kc = Ks[cur];
#pragma unroll
    for (int ni = 0; ni < 4; ++ni) {
      const int rb = (ni * 16 + lr) * 64;
      const short8 kf0 = *(const short8*)&Kc[rb + ((g * 8) ^ swz)];
      const short8 kf1 = *(const short8*)&Kc[rb + ((32 + g * 8) ^ swz)];
      floatx4 a = (floatx4){0.f, 0.f, 0.f, 0.f};
      a = MFMA16(q0, kf0, a);
      a = MFMA16(q1, kf1, a);
#pragma unroll
      for (int i = 0; i < 4; ++i) wacc[ni][i] += __expf(a[i] * 0.125f) * rl[i];
    }
    __syncthreads();
  }

#pragma unroll
  for (int ni = 0; ni < 4; ++ni)
#pragma unroll
    for (int i = 0; i < 4; ++i)
      Wout[((size_t)n * LSEQ + lrow + g * 4 + i) * LSEQ + s0 + ni * 16 + lr] = wacc[ni][i] * 0.0625f;
}

extern "C" void kernel_launch(void* const* d_in, const int* in_sizes, int n_in,
                              void* d_out, int out_size, void* d_ws, size_t ws_size,
                              hipStream_t stream) {
  const float* query = (const float*)d_in[0];
  const float* key   = (const float*)d_in[1];
  const float* value = (const float*)d_in[2];
  const float* Wq = (const float*)d_in[3]; const float* bq = (const float*)d_in[4];
  const float* Wk = (const float*)d_in[5]; const float* bk = (const float*)d_in[6];
  const float* Wv = (const float*)d_in[7]; const float* bv = (const float*)d_in[8];
  const float* Wo = (const float*)d_in[9]; const float* bo = (const float*)d_in[10];

  const size_t MB = 1u << 20;
  char* ws = (char*)d_ws;
  us* Xq  = (us*)(ws + 0 * MB);
  us* Xk  = (us*)(ws + 8 * MB);
  us* Xv  = (us*)(ws + 16 * MB);
  us* Wqb = (us*)(ws + 24 * MB);
  us* Wkb = (us*)(ws + 26 * MB);
  us* Wvb = (us*)(ws + 28 * MB);
  us* Wob = (us*)(ws + 30 * MB);
  us* qbuf = (us*)(ws + 32 * MB);
  us* kbuf = (us*)(ws + 40 * MB);
  us* Vt   = (us*)(ws + 48 * MB);
  us* Obuf = (us*)(ws + 56 * MB);
  float* ell = (float*)(ws + 64 * MB);

  // convert inputs to bf16
  k_f2bf<<<dim3(1024), 256, 0, stream>>>(query, Xq, 4096 * 1024 / 8);
  k_f2bf<<<dim3(1024), 256, 0, stream>>>(key,   Xk, 4096 * 1024 / 8);
  k_f2bf<<<dim3(1024), 256, 0, stream>>>(value, Xv, 4096 * 1024 / 8);
  k_f2bf<<<dim3(256), 256, 0, stream>>>(Wq, Wqb, 1024 * 1024 / 8);
  k_f2bf<<<dim3(256), 256, 0, stream>>>(Wk, Wkb, 1024 * 1024 / 8);
  k_f2bf<<<dim3(256), 256, 0, stream>>>(Wv, Wvb, 1024 * 1024 / 8);
  k_f2bf<<<dim3(256), 256, 0, stream>>>(Wo, Wob, 1024 * 1024 / 8);

  // fused q/k/v projections (z selects which)
  k_gemm_qkv<<<dim3(64, 8, 3), 256, 0, stream>>>(Xq, Xk, Xv, Wqb, Wkb, Wvb, bq, bk, bv,
                                                 qbuf, kbuf, Vt);

  // fused attention (writes Obuf bf16 + ell)
  k_attn<<<dim3(32, 32), 256, 0, stream>>>(qbuf, kbuf, Vt, ell, Obuf);

  // output projection (fp32 direct to d_out) + head-averaged weights
  k_gemm_o<<<dim3(64, 8), 256, 0, stream>>>(Obuf, Wob, bo, (float*)d_out);
  k_weights<<<dim3(32, 32, 2), 256, 0, stream>>>(qbuf, kbuf, ell, (float*)d_out + 4194304);
}

// Round 3
// 208.823 us; speedup vs baseline: 2.9680x; 1.0426x over previous
//
#include <hip/hip_runtime.h>

#define EDIM 1024
#define LSEQ 2048
#define NBATCH 2
#define NHEADS 16
#define HDIM 64

typedef unsigned short us;
typedef __attribute__((ext_vector_type(8))) short short8;
typedef __attribute__((ext_vector_type(4))) float floatx4;

#define MFMA16(a, b, c) __builtin_amdgcn_mfma_f32_16x16x32_bf16((a), (b), (c), 0, 0, 0)

__device__ __forceinline__ us f2bf(float f) {
  unsigned int u = __float_as_uint(f);
  u += 0x7fffu + ((u >> 16) & 1u);
  return (us)(u >> 16);
}

// async global -> LDS, 16B per lane; dst is wave-uniform base, lanes write base + lane*16
__device__ __forceinline__ void gload16(const void* g, void* l) {
  __builtin_amdgcn_global_load_lds((const __attribute__((address_space(1))) unsigned int*)g,
                                   (__attribute__((address_space(3))) unsigned int*)l, 16, 0, 0);
}

// ---------------- fp32 -> bf16 bulk convert, all 7 tensors in one launch ----------------
__global__ void k_f2bf_all(const float* q, const float* k, const float* v,
                           const float* wq, const float* wk, const float* wv, const float* wo,
                           us* dq, us* dk, us* dv, us* dwq, us* dwk, us* dwv, us* dwo) {
  const int z = blockIdx.y;
  const float* s; us* d; int n8;
  if (z == 0)      { s = q;  d = dq;  n8 = 524288; }
  else if (z == 1) { s = k;  d = dk;  n8 = 524288; }
  else if (z == 2) { s = v;  d = dv;  n8 = 524288; }
  else if (z == 3) { s = wq; d = dwq; n8 = 131072; }
  else if (z == 4) { s = wk; d = dwk; n8 = 131072; }
  else if (z == 5) { s = wv; d = dwv; n8 = 131072; }
  else             { s = wo; d = dwo; n8 = 131072; }
  int i = blockIdx.x * blockDim.x + threadIdx.x;
  int stride = gridDim.x * blockDim.x;
  for (; i < n8; i += stride) {
    float4 a = ((const float4*)s)[2 * i];
    float4 b = ((const float4*)s)[2 * i + 1];
    union { us u[8]; uint4 vv; } o;
    o.u[0] = f2bf(a.x); o.u[1] = f2bf(a.y); o.u[2] = f2bf(a.z); o.u[3] = f2bf(a.w);
    o.u[4] = f2bf(b.x); o.u[5] = f2bf(b.y); o.u[6] = f2bf(b.z); o.u[7] = f2bf(b.w);
    ((uint4*)d)[i] = o.vv;
  }
}

// ---------------- GEMM m97 structure: 128x128 tile, BK=32, 4 waves, 4x4 acc ----------------
// MODE 0: bf16 scatter [bh][seq][64]; MODE 1: bf16 -> Vt [bh][64][seq] via LDS transpose;
// MODE 2: fp32 direct.
template <int MODE>
__device__ __forceinline__ void gemm_core(us* pool,
                                          const us* __restrict__ A, const us* __restrict__ B,
                                          const float* __restrict__ bias, void* __restrict__ outp,
                                          int row0, int col0) {
  us* As = pool;          // [128][32]
  us* Bs = pool + 4096;   // [128][32]
  const int t = threadIdx.x;
  const int w = t >> 6, lane = t & 63;
  const int g = lane >> 4, lr = lane & 15;
  const int wm = (w & 1) * 64, wn = (w >> 1) * 64;
  const int srow = lane >> 2, scol = (lane & 3) * 8;  // 1KB chunk = 16 rows x 32 cols
  const int cA = 2 * w;
  const us* Asrc = A + (size_t)(row0 + cA * 16 + srow) * EDIM + scol;
  const us* Bsrc = B + (size_t)(col0 + cA * 16 + srow) * EDIM + scol;

  floatx4 acc[4][4];
#pragma unroll
  for (int mi = 0; mi < 4; ++mi)
#pragma unroll
    for (int ni = 0; ni < 4; ++ni) acc[mi][ni] = (floatx4){0.f, 0.f, 0.f, 0.f};

  for (int k0 = 0; k0 < EDIM; k0 += 32) {
    gload16(Asrc + k0, As + cA * 512);
    gload16(Asrc + 16 * EDIM + k0, As + cA * 512 + 512);
    gload16(Bsrc + k0, Bs + cA * 512);
    gload16(Bsrc + 16 * EDIM + k0, Bs + cA * 512 + 512);
    __syncthreads();
    short8 af[4], bfr[4];
#pragma unroll
    for (int mi = 0; mi < 4; ++mi) af[mi] = *(const short8*)&As[(wm + mi * 16 + lr) * 32 + g * 8];
#pragma unroll
    for (int ni = 0; ni < 4; ++ni) bfr[ni] = *(const short8*)&Bs[(wn + ni * 16 + lr) * 32 + g * 8];
#pragma unroll
    for (int mi = 0; mi < 4; ++mi)
#pragma unroll
      for (int ni = 0; ni < 4; ++ni) acc[mi][ni] = MFMA16(af[mi], bfr[ni], acc[mi][ni]);
    __syncthreads();
  }

  if (MODE == 1) {
    // transpose + n-deinterleave via LDS: Ct[col 0..127][n*64 + sqloc], row stride 136
    us* Ct = pool;  // 128*136 = 17408 elems
#pragma unroll
    for (int ni = 0; ni < 4; ++ni) {
      const int colloc = wn + ni * 16 + lr;
      const float bv = bias[col0 + colloc];
#pragma unroll
      for (int mi = 0; mi < 4; ++mi) {
        const int b = wm + mi * 16 + 4 * g;  // even
        unsigned int lo = (unsigned int)f2bf(acc[mi][ni][0] + bv) |
                          ((unsigned int)f2bf(acc[mi][ni][2] + bv) << 16);
        unsigned int hi = (unsigned int)f2bf(acc[mi][ni][1] + bv) |
                          ((unsigned int)f2bf(acc[mi][ni][3] + bv) << 16);
        *(unsigned int*)&Ct[colloc * 136 + (b >> 1)] = lo;
        *(unsigned int*)&Ct[colloc * 136 + 64 + (b >> 1)] = hi;
      }
    }
    __syncthreads();
    const int rr = t >> 1, half = t & 1;
    const int c = col0 + rr, h = c >> 6, d = c & 63;
    us* dst = (us*)outp + (((size_t)half * NHEADS + h) * HDIM + d) * LSEQ + (row0 >> 1);
    const us* srcRow = &Ct[rr * 136 + half * 64];
#pragma unroll
    for (int j = 0; j < 8; ++j)
      *(uint4*)(dst + j * 8) = *(const uint4*)(srcRow + j * 8);
  } else {
#pragma unroll
    for (int ni = 0; ni < 4; ++ni) {
      const int col = col0 + wn + ni * 16 + lr;
      const float bv = bias[col];
#pragma unroll
      for (int mi = 0; mi < 4; ++mi) {
#pragma unroll
        for (int i = 0; i < 4; ++i) {
          const int row = row0 + wm + mi * 16 + g * 4 + i;
          const float v = acc[mi][ni][i] + bv;
          if (MODE == 2) {
            ((float*)outp)[(size_t)row * EDIM + col] = v;
          } else {
            const int n = row & 1, sq = row >> 1;
            const int h = col >> 6, d = col & 63;
            ((us*)outp)[(((size_t)n * NHEADS + h) * LSEQ + sq) * HDIM + d] = f2bf(v);
          }
        }
      }
    }
  }
}

__global__ __launch_bounds__(256) void k_gemm_qkv(
    const us* __restrict__ Xq, const us* __restrict__ Xk, const us* __restrict__ Xv,
    const us* __restrict__ Wqb, const us* __restrict__ Wkb, const us* __restrict__ Wvb,
    const float* __restrict__ bq, const float* __restrict__ bk, const float* __restrict__ bv,
    us* __restrict__ qo, us* __restrict__ ko, us* __restrict__ vo) {
  __shared__ us pool[17408];
  const int z = blockIdx.z;
  if (z == 0)      gemm_core<0>(pool, Xq, Wqb, bq, qo, blockIdx.x * 128, blockIdx.y * 128);
  else if (z == 1) gemm_core<0>(pool, Xk, Wkb, bk, ko, blockIdx.x * 128, blockIdx.y * 128);
  else             gemm_core<1>(pool, Xv, Wvb, bv, vo, blockIdx.x * 128, blockIdx.y * 128);
}

__global__ __launch_bounds__(256) void k_gemm_o(const us* __restrict__ A, const us* __restrict__ B,
                                                const float* __restrict__ bias, float* __restrict__ out) {
  __shared__ us pool[8192];
  gemm_core<2>(pool, A, B, bias, out, blockIdx.x * 128, blockIdx.y * 128);
}

// ---------------- fused attention: O = softmax(QK^T/8) V, writes ell ----------------
// grid (bh=32, lblk=16), 256 thr, 32 q-rows per wave. K/V 64x64 double-buffered, XOR-swizzled.
__global__ __launch_bounds__(256) void k_attn(const us* __restrict__ qb, const us* __restrict__ kb,
                                              const us* __restrict__ vt, float* __restrict__ ell,
                                              us* __restrict__ O) {
  __shared__ us Ks[2][4096];
  __shared__ us Vs[2][4096];
  __shared__ us Ps[4][2048];  // per-wave 32 x 64
  const int bh = blockIdx.x;
  const int l0 = blockIdx.y * 128;
  const int t = threadIdx.x, w = t >> 6, lane = t & 63;
  const int g = lane >> 4, lr = lane & 15;
  const int lbase = l0 + w * 32;

  // Q fragments: two 16-row sub-tiles
  short8 q[2][2];
#pragma unroll
  for (int mi = 0; mi < 2; ++mi) {
    const us* qrow = qb + ((size_t)bh * LSEQ + lbase + mi * 16 + lr) * HDIM;
    q[mi][0] = *(const short8*)(qrow + g * 8);
    q[mi][1] = *(const short8*)(qrow + 32 + g * 8);
  }

  const int j0 = 2 * w, j1 = 2 * w + 1;
  const int srA = lane >> 3;
  const int scA = ((lane & 7) ^ (lane >> 3)) * 8;  // inverse-swizzled source col
  const us* Kbase = kb + (size_t)bh * LSEQ * HDIM;
  const us* Vbase = vt + (size_t)bh * HDIM * LSEQ;
  const us* Ksrc0 = Kbase + (j0 * 8 + srA) * HDIM + scA;
  const us* Ksrc1 = Kbase + (j1 * 8 + srA) * HDIM + scA;
  const us* Vsrc0 = Vbase + (size_t)(j0 * 8 + srA) * LSEQ + scA;
  const us* Vsrc1 = Vbase + (size_t)(j1 * 8 + srA) * LSEQ + scA;

  us* Pw = Ps[w];
  const int swz = (lr & 7) << 3;  // read-side XOR (elem units)

  floatx4 oacc[2][4];
#pragma unroll
  for (int mi = 0; mi < 2; ++mi)
#pragma unroll
    for (int ni = 0; ni < 4; ++ni) oacc[mi][ni] = (floatx4){0.f, 0.f, 0.f, 0.f};
  float ellacc[2][4] = {{0.f, 0.f, 0.f, 0.f}, {0.f, 0.f, 0.f, 0.f}};

  gload16(Ksrc0, &Ks[0][j0 * 512]); gload16(Ksrc1, &Ks[0][j1 * 512]);
  gload16(Vsrc0, &Vs[0][j0 * 512]); gload16(Vsrc1, &Vs[0][j1 * 512]);
  __syncthreads();

  for (int it = 0; it < 32; ++it) {
    const int cur = it & 1;
    if (it < 31) {
      const int so = (it + 1) * 64;
      us* Kn = Ks[cur ^ 1]; us* Vn = Vs[cur ^ 1];
      gload16(Ksrc0 + so * HDIM, Kn + j0 * 512);
      gload16(Ksrc1 + so * HDIM, Kn + j1 * 512);
      gload16(Vsrc0 + so, Vn + j0 * 512);
      gload16(Vsrc1 + so, Vn + j1 * 512);
    }
    const us* Kc = Ks[cur];
    const us* Vc = Vs[cur];

    // K fragments (shared by both mi sub-tiles)
    short8 kf[4][2];
#pragma unroll
    for (int ni = 0; ni < 4; ++ni) {
      const int rb = (ni * 16 + lr) * 64;
      kf[ni][0] = *(const short8*)&Kc[rb + ((g * 8) ^ swz)];
      kf[ni][1] = *(const short8*)&Kc[rb + ((32 + g * 8) ^ swz)];
    }
    floatx4 sacc[2][4];
#pragma unroll
    for (int mi = 0; mi < 2; ++mi)
#pragma unroll
      for (int ni = 0; ni < 4; ++ni) {
        floatx4 a = (floatx4){0.f, 0.f, 0.f, 0.f};
        a = MFMA16(q[mi][0], kf[ni][0], a);
        a = MFMA16(q[mi][1], kf[ni][1], a);
        sacc[mi][ni] = a;
      }
    // exp, ell accumulate, P -> LDS (row-swizzled)
#pragma unroll
    for (int mi = 0; mi < 2; ++mi)
#pragma unroll
      for (int i = 0; i < 4; ++i) {
        const int rsub = g * 4 + i;
        const int rx = (rsub & 7) << 3;
        us* prow = &Pw[(mi * 16 + rsub) * 64];
#pragma unroll
        for (int ni = 0; ni < 4; ++ni) {
          const float e = __expf(sacc[mi][ni][i] * 0.125f);
          ellacc[mi][i] += e;
          prow[(ni * 16 + lr) ^ rx] = f2bf(e);
        }
      }
    // PV
    short8 pf[2][2];
#pragma unroll
    for (int mi = 0; mi < 2; ++mi) {
      pf[mi][0] = *(const short8*)&Pw[(mi * 16 + lr) * 64 + ((g * 8) ^ swz)];
      pf[mi][1] = *(const short8*)&Pw[(mi * 16 + lr) * 64 + ((32 + g * 8) ^ swz)];
    }
#pragma unroll
    for (int ni = 0; ni < 4; ++ni) {
      const int rb = (ni * 16 + lr) * 64;
      const short8 vf0 = *(const short8*)&Vc[rb + ((g * 8) ^ swz)];
      const short8 vf1 = *(const short8*)&Vc[rb + ((32 + g * 8) ^ swz)];
#pragma unroll
      for (int mi = 0; mi < 2; ++mi) {
        oacc[mi][ni] = MFMA16(pf[mi][0], vf0, oacc[mi][ni]);
        oacc[mi][ni] = MFMA16(pf[mi][1], vf1, oacc[mi][ni]);
      }
    }
    __syncthreads();
  }

#pragma unroll
  for (int mi = 0; mi < 2; ++mi)
#pragma unroll
    for (int i = 0; i < 4; ++i) {
      float v = ellacc[mi][i];
      v += __shfl_xor(v, 1);
      v += __shfl_xor(v, 2);
      v += __shfl_xor(v, 4);
      v += __shfl_xor(v, 8);
      ellacc[mi][i] = v;
    }
  if (lr == 0) {
#pragma unroll
    for (int mi = 0; mi < 2; ++mi)
#pragma unroll
      for (int i = 0; i < 4; ++i)
        ell[bh * LSEQ + lbase + mi * 16 + g * 4 + i] = ellacc[mi][i];
  }

  const int n = bh >> 4, h = bh & 15;
#pragma unroll
  for (int mi = 0; mi < 2; ++mi)
#pragma unroll
    for (int i = 0; i < 4; ++i) {
      const int l = lbase + mi * 16 + g * 4 + i;
      const float rl = 1.0f / ellacc[mi][i];
#pragma unroll
      for (int ni = 0; ni < 4; ++ni)
        O[((size_t)l * NBATCH + n) * EDIM + h * HDIM + ni * 16 + lr] = f2bf(oacc[mi][ni][i] * rl);
    }
}

// ---------------- weights: W[n][l][s] = mean_h exp(q.k/8)/ell ----------------
// grid (lblk=16, sblk=32, n=2), 32 q-rows per wave. K tile LDS double-buffered over heads.
__global__ __launch_bounds__(256) void k_weights(const us* __restrict__ qb, const us* __restrict__ kb,
                                                 const float* __restrict__ ell, float* __restrict__ Wout) {
  __shared__ us Ks[2][4096];
  const int l0 = blockIdx.x * 128;
  const int s0 = blockIdx.y * 64;
  const int n = blockIdx.z;
  const int t = threadIdx.x, w = t >> 6, lane = t & 63;
  const int g = lane >> 4, lr = lane & 15;
  const int lbase = l0 + w * 32;
  const int j0 = 2 * w, j1 = 2 * w + 1;
  const int srA = lane >> 3;
  const int scA = ((lane & 7) ^ (lane >> 3)) * 8;
  const us* Kb0 = kb + ((size_t)(n * NHEADS) * LSEQ + s0 + j0 * 8 + srA) * HDIM + scA;
  const us* Kb1 = kb + ((size_t)(n * NHEADS) * LSEQ + s0 + j1 * 8 + srA) * HDIM + scA;
  const int swz = (lr & 7) << 3;

  float wacc[2][4][4];
#pragma unroll
  for (int mi = 0; mi < 2; ++mi)
#pragma unroll
    for (int ni = 0; ni < 4; ++ni)
#pragma unroll
      for (int i = 0; i < 4; ++i) wacc[mi][ni][i] = 0.f;

  gload16(Kb0, &Ks[0][j0 * 512]); gload16(Kb1, &Ks[0][j1 * 512]);
  __syncthreads();

  for (int h = 0; h < NHEADS; ++h) {
    const int cur = h & 1;
    if (h < NHEADS - 1) {
      us* Kn = Ks[cur ^ 1];
      gload16(Kb0 + (size_t)(h + 1) * LSEQ * HDIM, Kn + j0 * 512);
      gload16(Kb1 + (size_t)(h + 1) * LSEQ * HDIM, Kn + j1 * 512);
    }
    const int bh = n * NHEADS + h;
    short8 q[2][2];
    float rl[2][4];
#pragma unroll
    for (int mi = 0; mi < 2; ++mi) {
      const us* qrow = qb + ((size_t)bh * LSEQ + lbase + mi * 16 + lr) * HDIM;
      q[mi][0] = *(const short8*)(qrow + g * 8);
      q[mi][1] = *(const short8*)(qrow + 32 + g * 8);
#pragma unroll
      for (int i = 0; i < 4; ++i) rl[mi][i] = 1.0f / ell[bh * LSEQ + lbase + mi * 16 + g * 4 + i];
    }
    const us* Kc = Ks[cur];
    short8 kf[4][2];
#pragma unroll
    for (int ni = 0; ni < 4; ++ni) {
      const int rb = (ni * 16 + lr) * 64;
      kf[ni][0] = *(const short8*)&Kc[rb + ((g * 8) ^ swz)];
      kf[ni][1] = *(const short8*)&Kc[rb + ((32 + g * 8) ^ swz)];
    }
#pragma unroll
    for (int mi = 0; mi < 2; ++mi)
#pragma unroll
      for (int ni = 0; ni < 4; ++ni) {
        floatx4 a = (floatx4){0.f, 0.f, 0.f, 0.f};
        a = MFMA16(q[mi][0], kf[ni][0], a);
        a = MFMA16(q[mi][1], kf[ni][1], a);
#pragma unroll
        for (int i = 0; i < 4; ++i) wacc[mi][ni][i] += __expf(a[i] * 0.125f) * rl[mi][i];
      }
    __syncthreads();
  }

#pragma unroll
  for (int mi = 0; mi < 2; ++mi)
#pragma unroll
    for (int ni = 0; ni < 4; ++ni)
#pragma unroll
      for (int i = 0; i < 4; ++i)
        Wout[((size_t)n * LSEQ + lbase + mi * 16 + g * 4 + i) * LSEQ + s0 + ni * 16 + lr] =
            wacc[mi][ni][i] * 0.0625f;
}

extern "C" void kernel_launch(void* const* d_in, const int* in_sizes, int n_in,
                              void* d_out, int out_size, void* d_ws, size_t ws_size,
                              hipStream_t stream) {
  const float* query = (const float*)d_in[0];
  const float* key   = (const float*)d_in[1];
  const float* value = (const float*)d_in[2];
  const float* Wq = (const float*)d_in[3]; const float* bq = (const float*)d_in[4];
  const float* Wk = (const float*)d_in[5]; const float* bk = (const float*)d_in[6];
  const float* Wv = (const float*)d_in[7]; const float* bv = (const float*)d_in[8];
  const float* Wo = (const float*)d_in[9]; const float* bo = (const float*)d_in[10];

  const size_t MB = 1u << 20;
  char* ws = (char*)d_ws;
  us* Xq  = (us*)(ws + 0 * MB);
  us* Xk  = (us*)(ws + 8 * MB);
  us* Xv  = (us*)(ws + 16 * MB);
  us* Wqb = (us*)(ws + 24 * MB);
  us* Wkb = (us*)(ws + 26 * MB);
  us* Wvb = (us*)(ws + 28 * MB);
  us* Wob = (us*)(ws + 30 * MB);
  us* qbuf = (us*)(ws + 32 * MB);
  us* kbuf = (us*)(ws + 40 * MB);
  us* Vt   = (us*)(ws + 48 * MB);
  us* Obuf = (us*)(ws + 56 * MB);
  float* ell = (float*)(ws + 64 * MB);

  k_f2bf_all<<<dim3(256, 7), 256, 0, stream>>>(query, key, value, Wq, Wk, Wv, Wo,
                                               Xq, Xk, Xv, Wqb, Wkb, Wvb, Wob);

  // fused q/k/v projections, 128x128 tiles
  k_gemm_qkv<<<dim3(32, 8, 3), 256, 0, stream>>>(Xq, Xk, Xv, Wqb, Wkb, Wvb, bq, bk, bv,
                                                 qbuf, kbuf, Vt);

  // fused attention (writes Obuf bf16 + ell)
  k_attn<<<dim3(32, 16), 256, 0, stream>>>(qbuf, kbuf, Vt, ell, Obuf);

  // output projection (fp32 direct to d_out) + head-averaged weights
  k_gemm_o<<<dim3(32, 8), 256, 0, stream>>>(Obuf, Wob, bo, (float*)d_out);
  k_weights<<<dim3(16, 32, 2), 256, 0, stream>>>(qbuf, kbuf, ell, (float*)d_out + 4194304);
}

// Round 4
// 177.424 us; speedup vs baseline: 3.4932x; 1.1770x over previous
//
#include <hip/hip_runtime.h>

#define EDIM 1024
#define LSEQ 2048
#define NBATCH 2
#define NHEADS 16
#define HDIM 64
#define QSCALE 0.18033688011112042f  // log2(e)/8: exp(s/8) == exp2(s*QSCALE)

typedef unsigned short us;
typedef __attribute__((ext_vector_type(8))) short short8;
typedef __attribute__((ext_vector_type(4))) float floatx4;
typedef __attribute__((ext_vector_type(16))) float floatx16;

#define MFMA16(a, b, c) __builtin_amdgcn_mfma_f32_16x16x32_bf16((a), (b), (c), 0, 0, 0)
#define MFMA32(a, b, c) __builtin_amdgcn_mfma_f32_32x32x16_bf16((a), (b), (c), 0, 0, 0)
#define ZERO16 ((floatx16){0.f,0.f,0.f,0.f,0.f,0.f,0.f,0.f,0.f,0.f,0.f,0.f,0.f,0.f,0.f,0.f})

__device__ __forceinline__ us f2bf(float f) {
  unsigned int u = __float_as_uint(f);
  u += 0x7fffu + ((u >> 16) & 1u);
  return (us)(u >> 16);
}

__device__ __forceinline__ void gload16(const void* g, void* l) {
  __builtin_amdgcn_global_load_lds((const __attribute__((address_space(1))) unsigned int*)g,
                                   (__attribute__((address_space(3))) unsigned int*)l, 16, 0, 0);
}

__device__ __forceinline__ unsigned int cvtpk(float lo, float hi_) {
  unsigned int r;
  asm("v_cvt_pk_bf16_f32 %0, %1, %2" : "=v"(r) : "v"(lo), "v"(hi_));
  return r;
}
__device__ __forceinline__ void plswap(unsigned int& a, unsigned int& b) {
  asm("v_permlane32_swap_b32 %0, %1" : "+v"(a), "+v"(b));
}
__device__ __forceinline__ short8 mkfrag(unsigned int a, unsigned int b, unsigned int c,
                                         unsigned int d) {
  union { unsigned int u[4]; short8 v; } x;
  x.u[0] = a; x.u[1] = b; x.u[2] = c; x.u[3] = d;
  return x.v;
}
// acc (16 f32, rows crow(r,hi)) -> two PV A-fragments (k 0-15, k 16-31)
__device__ __forceinline__ void pack2(const floatx16 p, short8& f0, short8& f1) {
  unsigned int A = cvtpk(p[0], p[1]), B = cvtpk(p[4], p[5]); plswap(A, B);
  unsigned int C = cvtpk(p[2], p[3]), D = cvtpk(p[6], p[7]); plswap(C, D);
  f0 = mkfrag(A, C, B, D);
  unsigned int E = cvtpk(p[8], p[9]), F = cvtpk(p[12], p[13]); plswap(E, F);
  unsigned int G = cvtpk(p[10], p[11]), H = cvtpk(p[14], p[15]); plswap(G, H);
  f1 = mkfrag(E, G, F, H);
}

// ---------------- fp32 -> bf16 bulk convert, all 7 tensors in one launch ----------------
__global__ void k_f2bf_all(const float* q, const float* k, const float* v,
                           const float* wq, const float* wk, const float* wv, const float* wo,
                           us* dq, us* dk, us* dv, us* dwq, us* dwk, us* dwv, us* dwo) {
  const int z = blockIdx.y;
  const float* s; us* d; int n8;
  if (z == 0)      { s = q;  d = dq;  n8 = 524288; }
  else if (z == 1) { s = k;  d = dk;  n8 = 524288; }
  else if (z == 2) { s = v;  d = dv;  n8 = 524288; }
  else if (z == 3) { s = wq; d = dwq; n8 = 131072; }
  else if (z == 4) { s = wk; d = dwk; n8 = 131072; }
  else if (z == 5) { s = wv; d = dwv; n8 = 131072; }
  else             { s = wo; d = dwo; n8 = 131072; }
  int i = blockIdx.x * blockDim.x + threadIdx.x;
  int stride = gridDim.x * blockDim.x;
  for (; i < n8; i += stride) {
    float4 a = ((const float4*)s)[2 * i];
    float4 b = ((const float4*)s)[2 * i + 1];
    union { us u[8]; uint4 vv; } o;
    o.u[0] = f2bf(a.x); o.u[1] = f2bf(a.y); o.u[2] = f2bf(a.z); o.u[3] = f2bf(a.w);
    o.u[4] = f2bf(b.x); o.u[5] = f2bf(b.y); o.u[6] = f2bf(b.z); o.u[7] = f2bf(b.w);
    ((uint4*)d)[i] = o.vv;
  }
}

// ---------------- GEMM m97 structure: 128x128 tile, BK=32, 4 waves, 4x4 acc ----------------
template <int MODE>
__device__ __forceinline__ void gemm_core(us* pool,
                                          const us* __restrict__ A, const us* __restrict__ B,
                                          const float* __restrict__ bias, void* __restrict__ outp,
                                          int row0, int col0, float scale) {
  us* As = pool;          // [128][32]
  us* Bs = pool + 4096;   // [128][32]
  const int t = threadIdx.x;
  const int w = t >> 6, lane = t & 63;
  const int g = lane >> 4, lr = lane & 15;
  const int wm = (w & 1) * 64, wn = (w >> 1) * 64;
  const int srow = lane >> 2, scol = (lane & 3) * 8;
  const int cA = 2 * w;
  const us* Asrc = A + (size_t)(row0 + cA * 16 + srow) * EDIM + scol;
  const us* Bsrc = B + (size_t)(col0 + cA * 16 + srow) * EDIM + scol;

  floatx4 acc[4][4];
#pragma unroll
  for (int mi = 0; mi < 4; ++mi)
#pragma unroll
    for (int ni = 0; ni < 4; ++ni) acc[mi][ni] = (floatx4){0.f, 0.f, 0.f, 0.f};

  for (int k0 = 0; k0 < EDIM; k0 += 32) {
    gload16(Asrc + k0, As + cA * 512);
    gload16(Asrc + 16 * EDIM + k0, As + cA * 512 + 512);
    gload16(Bsrc + k0, Bs + cA * 512);
    gload16(Bsrc + 16 * EDIM + k0, Bs + cA * 512 + 512);
    __syncthreads();
    short8 af[4], bfr[4];
#pragma unroll
    for (int mi = 0; mi < 4; ++mi) af[mi] = *(const short8*)&As[(wm + mi * 16 + lr) * 32 + g * 8];
#pragma unroll
    for (int ni = 0; ni < 4; ++ni) bfr[ni] = *(const short8*)&Bs[(wn + ni * 16 + lr) * 32 + g * 8];
#pragma unroll
    for (int mi = 0; mi < 4; ++mi)
#pragma unroll
      for (int ni = 0; ni < 4; ++ni) acc[mi][ni] = MFMA16(af[mi], bfr[ni], acc[mi][ni]);
    __syncthreads();
  }

  if (MODE == 1) {
    // transpose + n-deinterleave via LDS -> Vt [bh][64][seq]
    us* Ct = pool;  // 128*136
#pragma unroll
    for (int ni = 0; ni < 4; ++ni) {
      const int colloc = wn + ni * 16 + lr;
      const float bv = bias[col0 + colloc];
#pragma unroll
      for (int mi = 0; mi < 4; ++mi) {
        const int b = wm + mi * 16 + 4 * g;
        unsigned int lo = (unsigned int)f2bf(acc[mi][ni][0] + bv) |
                          ((unsigned int)f2bf(acc[mi][ni][2] + bv) << 16);
        unsigned int hi = (unsigned int)f2bf(acc[mi][ni][1] + bv) |
                          ((unsigned int)f2bf(acc[mi][ni][3] + bv) << 16);
        *(unsigned int*)&Ct[colloc * 136 + (b >> 1)] = lo;
        *(unsigned int*)&Ct[colloc * 136 + 64 + (b >> 1)] = hi;
      }
    }
    __syncthreads();
    const int rr = t >> 1, half = t & 1;
    const int c = col0 + rr, h = c >> 6, d = c & 63;
    us* dst = (us*)outp + (((size_t)half * NHEADS + h) * HDIM + d) * LSEQ + (row0 >> 1);
    const us* srcRow = &Ct[rr * 136 + half * 64];
#pragma unroll
    for (int j = 0; j < 8; ++j)
      *(uint4*)(dst + j * 8) = *(const uint4*)(srcRow + j * 8);
  } else {
#pragma unroll
    for (int ni = 0; ni < 4; ++ni) {
      const int col = col0 + wn + ni * 16 + lr;
      const float bv = bias[col];
#pragma unroll
      for (int mi = 0; mi < 4; ++mi) {
#pragma unroll
        for (int i = 0; i < 4; ++i) {
          const int row = row0 + wm + mi * 16 + g * 4 + i;
          const float v = (acc[mi][ni][i] + bv) * scale;
          if (MODE == 2) {
            ((float*)outp)[(size_t)row * EDIM + col] = v;
          } else {
            const int n = row & 1, sq = row >> 1;
            const int h = col >> 6, d = col & 63;
            ((us*)outp)[(((size_t)n * NHEADS + h) * LSEQ + sq) * HDIM + d] = f2bf(v);
          }
        }
      }
    }
  }
}

__global__ __launch_bounds__(256) void k_gemm_qkv(
    const us* __restrict__ Xq, const us* __restrict__ Xk, const us* __restrict__ Xv,
    const us* __restrict__ Wqb, const us* __restrict__ Wkb, const us* __restrict__ Wvb,
    const float* __restrict__ bq, const float* __restrict__ bk, const float* __restrict__ bv,
    us* __restrict__ qo, us* __restrict__ ko, us* __restrict__ vo) {
  __shared__ us pool[17408];
  const int z = blockIdx.z;
  if (z == 0)      gemm_core<0>(pool, Xq, Wqb, bq, qo, blockIdx.x * 128, blockIdx.y * 128, QSCALE);
  else if (z == 1) gemm_core<0>(pool, Xk, Wkb, bk, ko, blockIdx.x * 128, blockIdx.y * 128, 1.0f);
  else             gemm_core<1>(pool, Xv, Wvb, bv, vo, blockIdx.x * 128, blockIdx.y * 128, 1.0f);
}

__global__ __launch_bounds__(256) void k_gemm_o(const us* __restrict__ A, const us* __restrict__ B,
                                                const float* __restrict__ bias, float* __restrict__ out) {
  __shared__ us pool[8192];
  gemm_core<2>(pool, A, B, bias, out, blockIdx.x * 128, blockIdx.y * 128, 1.0f);
}

// ---------------- fused attention, swapped QK^T + in-register P ----------------
// grid (bh=32, lblk=16), 256 thr, 32 q-rows/wave. K/V 64x64 dbuf LDS, XOR-swizzled.
__global__ __launch_bounds__(256) void k_attn(const us* __restrict__ qb, const us* __restrict__ kb,
                                              const us* __restrict__ vt, float* __restrict__ lgell,
                                              us* __restrict__ O) {
  __shared__ us Ks[2][4096];
  __shared__ us Vs[2][4096];
  __shared__ float elt[4][32];
  const int bh = blockIdx.x;
  const int l0 = blockIdx.y * 128;
  const int t = threadIdx.x, w = t >> 6, lane = t & 63;
  const int ql = lane & 31, hi = lane >> 5;

  // Q in registers: qf[dt] = Q[l0+w*32+ql][dt*16 + hi*8 .. +8]  (B-operand layout)
  short8 qf[4];
  {
    const us* qptr = qb + ((size_t)bh * LSEQ + l0 + w * 32 + ql) * HDIM + hi * 8;
#pragma unroll
    for (int dt = 0; dt < 4; ++dt) qf[dt] = *(const short8*)(qptr + dt * 16);
  }

  // swizzled LDS read offsets (rows ql and 32+ql, chunk (2j+hi)^(row&7))
  int off0[4], off1[4];
#pragma unroll
  for (int j = 0; j < 4; ++j) {
    off0[j] = ql * 64 + (((2 * j + hi) ^ (ql & 7)) << 3);
    off1[j] = (32 + ql) * 64 + (((2 * j + hi) ^ (ql & 7)) << 3);
  }

  const int j0 = 2 * w, j1 = 2 * w + 1;
  const int srA = lane >> 3;
  const int scA = ((lane & 7) ^ (lane >> 3)) * 8;
  const us* Kbase = kb + (size_t)bh * LSEQ * HDIM;
  const us* Vbase = vt + (size_t)bh * HDIM * LSEQ;
  const us* Ksrc0 = Kbase + (j0 * 8 + srA) * HDIM + scA;
  const us* Ksrc1 = Kbase + (j1 * 8 + srA) * HDIM + scA;
  const us* Vsrc0 = Vbase + (size_t)(j0 * 8 + srA) * LSEQ + scA;
  const us* Vsrc1 = Vbase + (size_t)(j1 * 8 + srA) * LSEQ + scA;

  floatx16 oacc0 = ZERO16, oacc1 = ZERO16;
  float ellacc = 0.f;

  gload16(Ksrc0, &Ks[0][j0 * 512]); gload16(Ksrc1, &Ks[0][j1 * 512]);
  gload16(Vsrc0, &Vs[0][j0 * 512]); gload16(Vsrc1, &Vs[0][j1 * 512]);
  __syncthreads();

  for (int it = 0; it < 32; ++it) {
    const int cur = it & 1;
    if (it < 31) {
      const int so = (it + 1) * 64;
      us* Kn = Ks[cur ^ 1]; us* Vn = Vs[cur ^ 1];
      gload16(Ksrc0 + so * HDIM, Kn + j0 * 512);
      gload16(Ksrc1 + so * HDIM, Kn + j1 * 512);
      gload16(Vsrc0 + so, Vn + j0 * 512);
      gload16(Vsrc1 + so, Vn + j1 * 512);
    }
    const us* Kc = Ks[cur];
    const us* Vc = Vs[cur];

    // S^T = K . Q^T : lane holds S[krow crow(r,hi)][qcol ql] for all 64 krows
    floatx16 acc0 = ZERO16, acc1 = ZERO16;
#pragma unroll
    for (int dt = 0; dt < 4; ++dt) {
      acc0 = MFMA32(*(const short8*)&Kc[off0[dt]], qf[dt], acc0);
      acc1 = MFMA32(*(const short8*)&Kc[off1[dt]], qf[dt], acc1);
    }
    // exp2 in place (Q pre-scaled by log2e/8), accumulate ell
#pragma unroll
    for (int r = 0; r < 16; ++r) {
      acc0[r] = __builtin_amdgcn_exp2f(acc0[r]); ellacc += acc0[r];
      acc1[r] = __builtin_amdgcn_exp2f(acc1[r]); ellacc += acc1[r];
    }
    // pack to PV A-fragments (k-slots 0..3 cover s-local 0..63)
    short8 pa0, pa1, pa2, pa3;
    pack2(acc0, pa0, pa1);
    pack2(acc1, pa2, pa3);
    // PV: O[q][d], B-frags from Vt rows d
#pragma unroll
    for (int dt2 = 0; dt2 < 2; ++dt2) {
      floatx16& oa = dt2 ? oacc1 : oacc0;
      const int* off = dt2 ? off1 : off0;
      oa = MFMA32(pa0, *(const short8*)&Vc[off[0]], oa);
      oa = MFMA32(pa1, *(const short8*)&Vc[off[1]], oa);
      oa = MFMA32(pa2, *(const short8*)&Vc[off[2]], oa);
      oa = MFMA32(pa3, *(const short8*)&Vc[off[3]], oa);
    }
    __syncthreads();
  }

  const float elltot = ellacc + __shfl_xor(ellacc, 32);
  if (lane < 32) {
    elt[w][lane] = 1.0f / elltot;
    lgell[(size_t)bh * LSEQ + l0 + w * 32 + lane] = __builtin_amdgcn_logf(elltot);
  }
  const int n = bh >> 4, hh = bh & 15;
  us* obase = O + (size_t)n * EDIM + (size_t)hh * HDIM;
#pragma unroll
  for (int r = 0; r < 16; ++r) {
    const int q = (r & 3) + 8 * (r >> 2) + 4 * hi;
    const float rl = elt[w][q];
    const size_t l = l0 + w * 32 + q;
    obase[l * (NBATCH * EDIM) + ql] = f2bf(oacc0[r] * rl);
    obase[l * (NBATCH * EDIM) + 32 + ql] = f2bf(oacc1[r] * rl);
  }
}

// ---------------- weights: W[n][l][s] = mean_h exp2(s* - log2 ell) ----------------
// grid (lblk=16, sblk=32, n=2), 32 q-rows/wave, non-swapped (coalesced s-writes).
__global__ __launch_bounds__(256) void k_weights(const us* __restrict__ qb, const us* __restrict__ kb,
                                                 const float* __restrict__ lgell,
                                                 float* __restrict__ Wout) {
  __shared__ us Ks[2][4096];
  __shared__ float lgt[4][32];
  const int l0 = blockIdx.x * 128;
  const int s0 = blockIdx.y * 64;
  const int n = blockIdx.z;
  const int t = threadIdx.x, w = t >> 6, lane = t & 63;
  const int ql = lane & 31, hi = lane >> 5;
  const int j0 = 2 * w, j1 = 2 * w + 1;
  const int srA = lane >> 3;
  const int scA = ((lane & 7) ^ (lane >> 3)) * 8;
  const us* Kb0 = kb + ((size_t)(n * NHEADS) * LSEQ + s0 + j0 * 8 + srA) * HDIM + scA;
  const us* Kb1 = kb + ((size_t)(n * NHEADS) * LSEQ + s0 + j1 * 8 + srA) * HDIM + scA;

  int off0[4], off1[4];
#pragma unroll
  for (int j = 0; j < 4; ++j) {
    off0[j] = ql * 64 + (((2 * j + hi) ^ (ql & 7)) << 3);
    off1[j] = (32 + ql) * 64 + (((2 * j + hi) ^ (ql & 7)) << 3);
  }

  floatx16 wacc0 = ZERO16, wacc1 = ZERO16;

  gload16(Kb0, &Ks[0][j0 * 512]); gload16(Kb1, &Ks[0][j1 * 512]);

  short8 qc[4], qn[4];
  float lgc, lgn = 0.f;
  {
    const us* qptr = qb + ((size_t)(n * NHEADS) * LSEQ + l0 + w * 32 + ql) * HDIM + hi * 8;
#pragma unroll
    for (int dt = 0; dt < 4; ++dt) qc[dt] = *(const short8*)(qptr + dt * 16);
  }
  lgc = (lane < 32) ? lgell[(size_t)(n * NHEADS) * LSEQ + l0 + w * 32 + lane] : 0.f;
  __syncthreads();

  for (int h = 0; h < NHEADS; ++h) {
    const int cur = h & 1;
    if (h < NHEADS - 1) {
      us* Kn2 = Ks[cur ^ 1];
      gload16(Kb0 + (size_t)(h + 1) * LSEQ * HDIM, Kn2 + j0 * 512);
      gload16(Kb1 + (size_t)(h + 1) * LSEQ * HDIM, Kn2 + j1 * 512);
      const us* qptr = qb + ((size_t)(n * NHEADS + h + 1) * LSEQ + l0 + w * 32 + ql) * HDIM + hi * 8;
#pragma unroll
      for (int dt = 0; dt < 4; ++dt) qn[dt] = *(const short8*)(qptr + dt * 16);
      if (lane < 32) lgn = lgell[(size_t)(n * NHEADS + h + 1) * LSEQ + l0 + w * 32 + lane];
    }
    if (lane < 32) lgt[w][lane] = lgc;
    const us* Kc = Ks[cur];
    floatx16 acc0 = ZERO16, acc1 = ZERO16;
#pragma unroll
    for (int dt = 0; dt < 4; ++dt) {
      acc0 = MFMA32(qc[dt], *(const short8*)&Kc[off0[dt]], acc0);
      acc1 = MFMA32(qc[dt], *(const short8*)&Kc[off1[dt]], acc1);
    }
#pragma unroll
    for (int r = 0; r < 16; ++r) {
      const float lg = lgt[w][(r & 3) + 8 * (r >> 2) + 4 * hi];
      wacc0[r] += __builtin_amdgcn_exp2f(acc0[r] - lg);
      wacc1[r] += __builtin_amdgcn_exp2f(acc1[r] - lg);
    }
#pragma unroll
    for (int dt = 0; dt < 4; ++dt) qc[dt] = qn[dt];
    lgc = lgn;
    __syncthreads();
  }

  float* wbase = Wout + (size_t)n * LSEQ * LSEQ + (size_t)s0;
#pragma unroll
  for (int r = 0; r < 16; ++r) {
    const int q = (r & 3) + 8 * (r >> 2) + 4 * hi;
    const size_t row = (size_t)(l0 + w * 32 + q) * LSEQ;
    wbase[row + ql] = wacc0[r] * 0.0625f;
    wbase[row + 32 + ql] = wacc1[r] * 0.0625f;
  }
}

extern "C" void kernel_launch(void* const* d_in, const int* in_sizes, int n_in,
                              void* d_out, int out_size, void* d_ws, size_t ws_size,
                              hipStream_t stream) {
  const float* query = (const float*)d_in[0];
  const float* key   = (const float*)d_in[1];
  const float* value = (const float*)d_in[2];
  const float* Wq = (const float*)d_in[3]; const float* bq = (const float*)d_in[4];
  const float* Wk = (const float*)d_in[5]; const float* bk = (const float*)d_in[6];
  const float* Wv = (const float*)d_in[7]; const float* bv = (const float*)d_in[8];
  const float* Wo = (const float*)d_in[9]; const float* bo = (const float*)d_in[10];

  const size_t MB = 1u << 20;
  char* ws = (char*)d_ws;
  us* Xq  = (us*)(ws + 0 * MB);
  us* Xk  = (us*)(ws + 8 * MB);
  us* Xv  = (us*)(ws + 16 * MB);
  us* Wqb = (us*)(ws + 24 * MB);
  us* Wkb = (us*)(ws + 26 * MB);
  us* Wvb = (us*)(ws + 28 * MB);
  us* Wob = (us*)(ws + 30 * MB);
  us* qbuf = (us*)(ws + 32 * MB);
  us* kbuf = (us*)(ws + 40 * MB);
  us* Vt   = (us*)(ws + 48 * MB);
  us* Obuf = (us*)(ws + 56 * MB);
  float* lgell = (float*)(ws + 64 * MB);

  k_f2bf_all<<<dim3(256, 7), 256, 0, stream>>>(query, key, value, Wq, Wk, Wv, Wo,
                                               Xq, Xk, Xv, Wqb, Wkb, Wvb, Wob);

  k_gemm_qkv<<<dim3(32, 8, 3), 256, 0, stream>>>(Xq, Xk, Xv, Wqb, Wkb, Wvb, bq, bk, bv,
                                                 qbuf, kbuf, Vt);

  k_attn<<<dim3(32, 16), 256, 0, stream>>>(qbuf, kbuf, Vt, lgell, Obuf);

  k_gemm_o<<<dim3(32, 8), 256, 0, stream>>>(Obuf, Wob, bo, (float*)d_out);
  k_weights<<<dim3(16, 32, 2), 256, 0, stream>>>(qbuf, kbuf, lgell, (float*)d_out + 4194304);
}

// Round 6
// 173.314 us; speedup vs baseline: 3.5761x; 1.0237x over previous
//
#include <hip/hip_runtime.h>

#define EDIM 1024
#define LSEQ 2048
#define NBATCH 2
#define NHEADS 16
#define HDIM 64
#define QSCALE 0.18033688011112042f  // log2(e)/8: exp(s/8) == exp2(s*QSCALE)

typedef unsigned short us;
typedef __attribute__((ext_vector_type(8))) short short8;
typedef __attribute__((ext_vector_type(4))) float floatx4;
typedef __attribute__((ext_vector_type(16))) float floatx16;

#define MFMA16(a, b, c) __builtin_amdgcn_mfma_f32_16x16x32_bf16((a), (b), (c), 0, 0, 0)
#define MFMA32(a, b, c) __builtin_amdgcn_mfma_f32_32x32x16_bf16((a), (b), (c), 0, 0, 0)
#define ZERO16 ((floatx16){0.f,0.f,0.f,0.f,0.f,0.f,0.f,0.f,0.f,0.f,0.f,0.f,0.f,0.f,0.f,0.f})

__device__ __forceinline__ us f2bf(float f) {
  unsigned int u = __float_as_uint(f);
  u += 0x7fffu + ((u >> 16) & 1u);
  return (us)(u >> 16);
}

__device__ __forceinline__ void gload16(const void* g, void* l) {
  __builtin_amdgcn_global_load_lds((const __attribute__((address_space(1))) unsigned int*)g,
                                   (__attribute__((address_space(3))) unsigned int*)l, 16, 0, 0);
}

__device__ __forceinline__ unsigned int cvtpk(float lo, float hi_) {
  unsigned int r;
  asm("v_cvt_pk_bf16_f32 %0, %1, %2" : "=v"(r) : "v"(lo), "v"(hi_));
  return r;
}
__device__ __forceinline__ void plswap(unsigned int& a, unsigned int& b) {
  asm("v_permlane32_swap_b32 %0, %1" : "+v"(a), "+v"(b));
}
__device__ __forceinline__ short8 mkfrag(unsigned int a, unsigned int b, unsigned int c,
                                         unsigned int d) {
  union { unsigned int u[4]; short8 v; } x;
  x.u[0] = a; x.u[1] = b; x.u[2] = c; x.u[3] = d;
  return x.v;
}
// acc (16 f32, rows crow(r,hi)) -> two PV A-fragments (k 0-15, k 16-31)
__device__ __forceinline__ void pack2(const floatx16 p, short8& f0, short8& f1) {
  unsigned int A = cvtpk(p[0], p[1]), B = cvtpk(p[4], p[5]); plswap(A, B);
  unsigned int C = cvtpk(p[2], p[3]), D = cvtpk(p[6], p[7]); plswap(C, D);
  f0 = mkfrag(A, C, B, D);
  unsigned int E = cvtpk(p[8], p[9]), F = cvtpk(p[12], p[13]); plswap(E, F);
  unsigned int G = cvtpk(p[10], p[11]), H = cvtpk(p[14], p[15]); plswap(G, H);
  f1 = mkfrag(E, G, F, H);
}

// ---------------- fp32 -> bf16 bulk convert, all 7 tensors in one launch ----------------
__global__ void k_f2bf_all(const float* q, const float* k, const float* v,
                           const float* wq, const float* wk, const float* wv, const float* wo,
                           us* dq, us* dk, us* dv, us* dwq, us* dwk, us* dwv, us* dwo) {
  const int z = blockIdx.y;
  const float* s; us* d; int n8;
  if (z == 0)      { s = q;  d = dq;  n8 = 524288; }
  else if (z == 1) { s = k;  d = dk;  n8 = 524288; }
  else if (z == 2) { s = v;  d = dv;  n8 = 524288; }
  else if (z == 3) { s = wq; d = dwq; n8 = 131072; }
  else if (z == 4) { s = wk; d = dwk; n8 = 131072; }
  else if (z == 5) { s = wv; d = dwv; n8 = 131072; }
  else             { s = wo; d = dwo; n8 = 131072; }
  int i = blockIdx.x * blockDim.x + threadIdx.x;
  int stride = gridDim.x * blockDim.x;
  for (; i < n8; i += stride) {
    float4 a = ((const float4*)s)[2 * i];
    float4 b = ((const float4*)s)[2 * i + 1];
    union { us u[8]; uint4 vv; } o;
    o.u[0] = f2bf(a.x); o.u[1] = f2bf(a.y); o.u[2] = f2bf(a.z); o.u[3] = f2bf(a.w);
    o.u[4] = f2bf(b.x); o.u[5] = f2bf(b.y); o.u[6] = f2bf(b.z); o.u[7] = f2bf(b.w);
    ((uint4*)d)[i] = o.vv;
  }
}

// ---------------- GEMM m97 structure: 128x128 tile, BK=32, 4 waves, 4x4 acc ----------------
template <int MODE>
__device__ __forceinline__ void gemm_core(us* pool,
                                          const us* __restrict__ A, const us* __restrict__ B,
                                          const float* __restrict__ bias, void* __restrict__ outp,
                                          int row0, int col0, float scale) {
  us* As = pool;          // [128][32]
  us* Bs = pool + 4096;   // [128][32]
  const int t = threadIdx.x;
  const int w = t >> 6, lane = t & 63;
  const int g = lane >> 4, lr = lane & 15;
  const int wm = (w & 1) * 64, wn = (w >> 1) * 64;
  const int srow = lane >> 2, scol = (lane & 3) * 8;
  const int cA = 2 * w;
  const us* Asrc = A + (size_t)(row0 + cA * 16 + srow) * EDIM + scol;
  const us* Bsrc = B + (size_t)(col0 + cA * 16 + srow) * EDIM + scol;

  floatx4 acc[4][4];
#pragma unroll
  for (int mi = 0; mi < 4; ++mi)
#pragma unroll
    for (int ni = 0; ni < 4; ++ni) acc[mi][ni] = (floatx4){0.f, 0.f, 0.f, 0.f};

  for (int k0 = 0; k0 < EDIM; k0 += 32) {
    gload16(Asrc + k0, As + cA * 512);
    gload16(Asrc + 16 * EDIM + k0, As + cA * 512 + 512);
    gload16(Bsrc + k0, Bs + cA * 512);
    gload16(Bsrc + 16 * EDIM + k0, Bs + cA * 512 + 512);
    __syncthreads();
    short8 af[4], bfr[4];
#pragma unroll
    for (int mi = 0; mi < 4; ++mi) af[mi] = *(const short8*)&As[(wm + mi * 16 + lr) * 32 + g * 8];
#pragma unroll
    for (int ni = 0; ni < 4; ++ni) bfr[ni] = *(const short8*)&Bs[(wn + ni * 16 + lr) * 32 + g * 8];
#pragma unroll
    for (int mi = 0; mi < 4; ++mi)
#pragma unroll
      for (int ni = 0; ni < 4; ++ni) acc[mi][ni] = MFMA16(af[mi], bfr[ni], acc[mi][ni]);
    __syncthreads();
  }

  if (MODE == 1) {
    us* Ct = pool;  // 128*136
#pragma unroll
    for (int ni = 0; ni < 4; ++ni) {
      const int colloc = wn + ni * 16 + lr;
      const float bv = bias[col0 + colloc];
#pragma unroll
      for (int mi = 0; mi < 4; ++mi) {
        const int b = wm + mi * 16 + 4 * g;
        unsigned int lo = (unsigned int)f2bf(acc[mi][ni][0] + bv) |
                          ((unsigned int)f2bf(acc[mi][ni][2] + bv) << 16);
        unsigned int hi = (unsigned int)f2bf(acc[mi][ni][1] + bv) |
                          ((unsigned int)f2bf(acc[mi][ni][3] + bv) << 16);
        *(unsigned int*)&Ct[colloc * 136 + (b >> 1)] = lo;
        *(unsigned int*)&Ct[colloc * 136 + 64 + (b >> 1)] = hi;
      }
    }
    __syncthreads();
    const int rr = t >> 1, half = t & 1;
    const int c = col0 + rr, h = c >> 6, d = c & 63;
    us* dst = (us*)outp + (((size_t)half * NHEADS + h) * HDIM + d) * LSEQ + (row0 >> 1);
    const us* srcRow = &Ct[rr * 136 + half * 64];
#pragma unroll
    for (int j = 0; j < 8; ++j)
      *(uint4*)(dst + j * 8) = *(const uint4*)(srcRow + j * 8);
  } else {
#pragma unroll
    for (int ni = 0; ni < 4; ++ni) {
      const int col = col0 + wn + ni * 16 + lr;
      const float bv = bias[col];
#pragma unroll
      for (int mi = 0; mi < 4; ++mi) {
#pragma unroll
        for (int i = 0; i < 4; ++i) {
          const int row = row0 + wm + mi * 16 + g * 4 + i;
          const float v = (acc[mi][ni][i] + bv) * scale;
          if (MODE == 2) {
            ((float*)outp)[(size_t)row * EDIM + col] = v;
          } else {
            const int n = row & 1, sq = row >> 1;
            const int h = col >> 6, d = col & 63;
            ((us*)outp)[(((size_t)n * NHEADS + h) * LSEQ + sq) * HDIM + d] = f2bf(v);
          }
        }
      }
    }
  }
}

__global__ __launch_bounds__(256) void k_gemm_qkv(
    const us* __restrict__ Xq, const us* __restrict__ Xk, const us* __restrict__ Xv,
    const us* __restrict__ Wqb, const us* __restrict__ Wkb, const us* __restrict__ Wvb,
    const float* __restrict__ bq, const float* __restrict__ bk, const float* __restrict__ bv,
    us* __restrict__ qo, us* __restrict__ ko, us* __restrict__ vo) {
  __shared__ us pool[17408];
  const int z = blockIdx.z;
  if (z == 0)      gemm_core<0>(pool, Xq, Wqb, bq, qo, blockIdx.x * 128, blockIdx.y * 128, QSCALE);
  else if (z == 1) gemm_core<0>(pool, Xk, Wkb, bk, ko, blockIdx.x * 128, blockIdx.y * 128, 1.0f);
  else             gemm_core<1>(pool, Xv, Wvb, bv, vo, blockIdx.x * 128, blockIdx.y * 128, 1.0f);
}

__global__ __launch_bounds__(256) void k_gemm_o(const us* __restrict__ A, const us* __restrict__ B,
                                                const float* __restrict__ bias, float* __restrict__ out) {
  __shared__ us pool[8192];
  gemm_core<2>(pool, A, B, bias, out, blockIdx.x * 128, blockIdx.y * 128, 1.0f);
}

// ---------------- fused attention (R4-proven 32-row/wave), stores 1/ell ----------------
// grid (bh=32, lblk=16), 256 thr. K/V 64x64 dbuf LDS, XOR-swizzled.
__global__ __launch_bounds__(256) void k_attn(const us* __restrict__ qb, const us* __restrict__ kb,
                                              const us* __restrict__ vt, float* __restrict__ rell,
                                              us* __restrict__ O) {
  __shared__ us Ks[2][4096];
  __shared__ us Vs[2][4096];
  __shared__ float elt[4][32];
  const int bh = blockIdx.x;
  const int l0 = blockIdx.y * 128;
  const int t = threadIdx.x, w = t >> 6, lane = t & 63;
  const int ql = lane & 31, hi = lane >> 5;

  // Q in registers: qf[dt] = Q[l0+w*32+ql][dt*16 + hi*8 .. +8]  (B-operand layout)
  short8 qf[4];
  {
    const us* qptr = qb + ((size_t)bh * LSEQ + l0 + w * 32 + ql) * HDIM + hi * 8;
#pragma unroll
    for (int dt = 0; dt < 4; ++dt) qf[dt] = *(const short8*)(qptr + dt * 16);
  }

  // swizzled LDS read offsets (rows ql and 32+ql, chunk (2j+hi)^(row&7))
  int off0[4], off1[4];
#pragma unroll
  for (int j = 0; j < 4; ++j) {
    off0[j] = ql * 64 + (((2 * j + hi) ^ (ql & 7)) << 3);
    off1[j] = (32 + ql) * 64 + (((2 * j + hi) ^ (ql & 7)) << 3);
  }

  const int j0 = 2 * w, j1 = 2 * w + 1;
  const int srA = lane >> 3;
  const int scA = ((lane & 7) ^ (lane >> 3)) * 8;
  const us* Kbase = kb + (size_t)bh * LSEQ * HDIM;
  const us* Vbase = vt + (size_t)bh * HDIM * LSEQ;
  const us* Ksrc0 = Kbase + (j0 * 8 + srA) * HDIM + scA;
  const us* Ksrc1 = Kbase + (j1 * 8 + srA) * HDIM + scA;
  const us* Vsrc0 = Vbase + (size_t)(j0 * 8 + srA) * LSEQ + scA;
  const us* Vsrc1 = Vbase + (size_t)(j1 * 8 + srA) * LSEQ + scA;

  floatx16 oacc0 = ZERO16, oacc1 = ZERO16;
  float ellacc = 0.f;

  gload16(Ksrc0, &Ks[0][j0 * 512]); gload16(Ksrc1, &Ks[0][j1 * 512]);
  gload16(Vsrc0, &Vs[0][j0 * 512]); gload16(Vsrc1, &Vs[0][j1 * 512]);
  __syncthreads();

  for (int it = 0; it < 32; ++it) {
    const int cur = it & 1;
    if (it < 31) {
      const int so = (it + 1) * 64;
      us* Kn = Ks[cur ^ 1]; us* Vn = Vs[cur ^ 1];
      gload16(Ksrc0 + so * HDIM, Kn + j0 * 512);
      gload16(Ksrc1 + so * HDIM, Kn + j1 * 512);
      gload16(Vsrc0 + so, Vn + j0 * 512);
      gload16(Vsrc1 + so, Vn + j1 * 512);
    }
    const us* Kc = Ks[cur];
    const us* Vc = Vs[cur];

    // S^T = K . Q^T : lane holds S[krow crow(r,hi)][qcol ql] for all 64 krows
    floatx16 acc0 = ZERO16, acc1 = ZERO16;
#pragma unroll
    for (int dt = 0; dt < 4; ++dt) {
      acc0 = MFMA32(*(const short8*)&Kc[off0[dt]], qf[dt], acc0);
      acc1 = MFMA32(*(const short8*)&Kc[off1[dt]], qf[dt], acc1);
    }
    // exp2 in place (Q pre-scaled by log2e/8), accumulate ell
#pragma unroll
    for (int r = 0; r < 16; ++r) {
      acc0[r] = __builtin_amdgcn_exp2f(acc0[r]); ellacc += acc0[r];
      acc1[r] = __builtin_amdgcn_exp2f(acc1[r]); ellacc += acc1[r];
    }
    // pack to PV A-fragments (k-slots 0..3 cover s-local 0..63)
    short8 pa0, pa1, pa2, pa3;
    pack2(acc0, pa0, pa1);
    pack2(acc1, pa2, pa3);
    // PV: O[q][d], B-frags from Vt rows d
#pragma unroll
    for (int dt2 = 0; dt2 < 2; ++dt2) {
      floatx16& oa = dt2 ? oacc1 : oacc0;
      const int* off = dt2 ? off1 : off0;
      oa = MFMA32(pa0, *(const short8*)&Vc[off[0]], oa);
      oa = MFMA32(pa1, *(const short8*)&Vc[off[1]], oa);
      oa = MFMA32(pa2, *(const short8*)&Vc[off[2]], oa);
      oa = MFMA32(pa3, *(const short8*)&Vc[off[3]], oa);
    }
    __syncthreads();
  }

  const float elltot = ellacc + __shfl_xor(ellacc, 32);
  if (lane < 32) {
    const float r0 = 1.0f / elltot;
    elt[w][lane] = r0;
    rell[(size_t)bh * LSEQ + l0 + w * 32 + lane] = r0;
  }
  const int n = bh >> 4, hh = bh & 15;
  us* obase = O + (size_t)n * EDIM + (size_t)hh * HDIM;
#pragma unroll
  for (int r = 0; r < 16; ++r) {
    const int q = (r & 3) + 8 * (r >> 2) + 4 * hi;
    const float rl = elt[w][q];
    const size_t l = l0 + w * 32 + q;
    obase[l * (NBATCH * EDIM) + ql] = f2bf(oacc0[r] * rl);
    obase[l * (NBATCH * EDIM) + 32 + ql] = f2bf(oacc1[r] * rl);
  }
}

// ---------------- weights (swapped): W[n][l][s] = mean_h exp2(s*) / ell ----------------
// grid (lblk=8, sblk=32, n=2), QBLK=64/wave. Per-lane 1/ell scalar; K LDS dbuf over heads.
__global__ __launch_bounds__(256, 2) void k_weights(const us* __restrict__ qb, const us* __restrict__ kb,
                                                    const float* __restrict__ rell,
                                                    float* __restrict__ Wout) {
  __shared__ us Ks[2][4096];
  const int l0 = blockIdx.x * 256;
  const int s0 = blockIdx.y * 64;
  const int n = blockIdx.z;
  const int t = threadIdx.x, w = t >> 6, lane = t & 63;
  const int ql = lane & 31, hi = lane >> 5;
  const int lbase = l0 + w * 64;
  const int j0 = 2 * w, j1 = 2 * w + 1;
  const int srA = lane >> 3;
  const int scA = ((lane & 7) ^ (lane >> 3)) * 8;
  const us* Kb0 = kb + ((size_t)(n * NHEADS) * LSEQ + s0 + j0 * 8 + srA) * HDIM + scA;
  const us* Kb1 = kb + ((size_t)(n * NHEADS) * LSEQ + s0 + j1 * 8 + srA) * HDIM + scA;

  int off0[4], off1[4];
#pragma unroll
  for (int j = 0; j < 4; ++j) {
    off0[j] = ql * 64 + (((2 * j + hi) ^ (ql & 7)) << 3);
    off1[j] = (32 + ql) * 64 + (((2 * j + hi) ^ (ql & 7)) << 3);
  }

  floatx16 wa00 = ZERO16, wa01 = ZERO16, wa10 = ZERO16, wa11 = ZERO16;

  gload16(Kb0, &Ks[0][j0 * 512]); gload16(Kb1, &Ks[0][j1 * 512]);

  // current-head Q fragments + 1/ell (per-lane scalars)
  short8 qc0[4], qc1[4];
  float rlc0, rlc1;
  {
    const us* qp0 = qb + ((size_t)(n * NHEADS) * LSEQ + lbase + ql) * HDIM + hi * 8;
    const us* qp1 = qp0 + 32 * HDIM;
#pragma unroll
    for (int dt = 0; dt < 4; ++dt) {
      qc0[dt] = *(const short8*)(qp0 + dt * 16);
      qc1[dt] = *(const short8*)(qp1 + dt * 16);
    }
    rlc0 = rell[(size_t)(n * NHEADS) * LSEQ + lbase + ql];
    rlc1 = rell[(size_t)(n * NHEADS) * LSEQ + lbase + 32 + ql];
  }
  __syncthreads();

  for (int h = 0; h < NHEADS; ++h) {
    const int cur = h & 1;
    short8 qn0[4], qn1[4];
    float rln0 = 0.f, rln1 = 0.f;
    if (h < NHEADS - 1) {
      us* Kn2 = Ks[cur ^ 1];
      gload16(Kb0 + (size_t)(h + 1) * LSEQ * HDIM, Kn2 + j0 * 512);
      gload16(Kb1 + (size_t)(h + 1) * LSEQ * HDIM, Kn2 + j1 * 512);
      const us* qp0 = qb + ((size_t)(n * NHEADS + h + 1) * LSEQ + lbase + ql) * HDIM + hi * 8;
      const us* qp1 = qp0 + 32 * HDIM;
#pragma unroll
      for (int dt = 0; dt < 4; ++dt) {
        qn0[dt] = *(const short8*)(qp0 + dt * 16);
        qn1[dt] = *(const short8*)(qp1 + dt * 16);
      }
      rln0 = rell[(size_t)(n * NHEADS + h + 1) * LSEQ + lbase + ql];
      rln1 = rell[(size_t)(n * NHEADS + h + 1) * LSEQ + lbase + 32 + ql];
    }
    const us* Kc = Ks[cur];
    short8 kf0[4], kf1[4];
#pragma unroll
    for (int dt = 0; dt < 4; ++dt) {
      kf0[dt] = *(const short8*)&Kc[off0[dt]];
      kf1[dt] = *(const short8*)&Kc[off1[dt]];
    }
    {
      floatx16 aA = ZERO16, aB = ZERO16;
#pragma unroll
      for (int dt = 0; dt < 4; ++dt) {
        aA = MFMA32(kf0[dt], qc0[dt], aA);
        aB = MFMA32(kf1[dt], qc0[dt], aB);
      }
#pragma unroll
      for (int r = 0; r < 16; ++r) {
        wa00[r] += __builtin_amdgcn_exp2f(aA[r]) * rlc0;
        wa01[r] += __builtin_amdgcn_exp2f(aB[r]) * rlc0;
      }
    }
    {
      floatx16 cA = ZERO16, cB = ZERO16;
#pragma unroll
      for (int dt = 0; dt < 4; ++dt) {
        cA = MFMA32(kf0[dt], qc1[dt], cA);
        cB = MFMA32(kf1[dt], qc1[dt], cB);
      }
#pragma unroll
      for (int r = 0; r < 16; ++r) {
        wa10[r] += __builtin_amdgcn_exp2f(cA[r]) * rlc1;
        wa11[r] += __builtin_amdgcn_exp2f(cB[r]) * rlc1;
      }
    }
#pragma unroll
    for (int dt = 0; dt < 4; ++dt) { qc0[dt] = qn0[dt]; qc1[dt] = qn1[dt]; }
    rlc0 = rln0; rlc1 = rln1;
    __syncthreads();
  }

  // write: lane owns rows q = lbase + qh*32 + ql; cols s = s0 + sh*32 + crow(r,hi)
  float* wb0 = Wout + (size_t)n * LSEQ * LSEQ + (size_t)(lbase + ql) * LSEQ + s0;
  float* wb1 = Wout + (size_t)n * LSEQ * LSEQ + (size_t)(lbase + 32 + ql) * LSEQ + s0;
#pragma unroll
  for (int r = 0; r < 16; ++r) {
    const int cr = (r & 3) + 8 * (r >> 2) + 4 * hi;
    wb0[cr] = wa00[r] * 0.0625f;
    wb0[32 + cr] = wa01[r] * 0.0625f;
    wb1[cr] = wa10[r] * 0.0625f;
    wb1[32 + cr] = wa11[r] * 0.0625f;
  }
}

extern "C" void kernel_launch(void* const* d_in, const int* in_sizes, int n_in,
                              void* d_out, int out_size, void* d_ws, size_t ws_size,
                              hipStream_t stream) {
  const float* query = (const float*)d_in[0];
  const float* key   = (const float*)d_in[1];
  const float* value = (const float*)d_in[2];
  const float* Wq = (const float*)d_in[3]; const float* bq = (const float*)d_in[4];
  const float* Wk = (const float*)d_in[5]; const float* bk = (const float*)d_in[6];
  const float* Wv = (const float*)d_in[7]; const float* bv = (const float*)d_in[8];
  const float* Wo = (const float*)d_in[9]; const float* bo = (const float*)d_in[10];

  const size_t MB = 1u << 20;
  char* ws = (char*)d_ws;
  us* Xq  = (us*)(ws + 0 * MB);
  us* Xk  = (us*)(ws + 8 * MB);
  us* Xv  = (us*)(ws + 16 * MB);
  us* Wqb = (us*)(ws + 24 * MB);
  us* Wkb = (us*)(ws + 26 * MB);
  us* Wvb = (us*)(ws + 28 * MB);
  us* Wob = (us*)(ws + 30 * MB);
  us* qbuf = (us*)(ws + 32 * MB);
  us* kbuf = (us*)(ws + 40 * MB);
  us* Vt   = (us*)(ws + 48 * MB);
  us* Obuf = (us*)(ws + 56 * MB);
  float* rell = (float*)(ws + 64 * MB);

  k_f2bf_all<<<dim3(256, 7), 256, 0, stream>>>(query, key, value, Wq, Wk, Wv, Wo,
                                               Xq, Xk, Xv, Wqb, Wkb, Wvb, Wob);

  k_gemm_qkv<<<dim3(32, 8, 3), 256, 0, stream>>>(Xq, Xk, Xv, Wqb, Wkb, Wvb, bq, bk, bv,
                                                 qbuf, kbuf, Vt);

  k_attn<<<dim3(32, 16), 256, 0, stream>>>(qbuf, kbuf, Vt, rell, Obuf);

  k_gemm_o<<<dim3(32, 8), 256, 0, stream>>>(Obuf, Wob, bo, (float*)d_out);
  k_weights<<<dim3(8, 32, 2), 256, 0, stream>>>(qbuf, kbuf, rell, (float*)d_out + 4194304);
}

// Round 7
// 171.565 us; speedup vs baseline: 3.6125x; 1.0102x over previous
//
#include <hip/hip_runtime.h>

#define EDIM 1024
#define LSEQ 2048
#define NBATCH 2
#define NHEADS 16
#define HDIM 64
#define QSCALE 0.18033688011112042f  // log2(e)/8: exp(s/8) == exp2(s*QSCALE)

typedef unsigned short us;
typedef __attribute__((ext_vector_type(8))) short short8;
typedef __attribute__((ext_vector_type(4))) float floatx4;
typedef __attribute__((ext_vector_type(16))) float floatx16;

#define MFMA16(a, b, c) __builtin_amdgcn_mfma_f32_16x16x32_bf16((a), (b), (c), 0, 0, 0)
#define MFMA32(a, b, c) __builtin_amdgcn_mfma_f32_32x32x16_bf16((a), (b), (c), 0, 0, 0)
#define ZERO16 ((floatx16){0.f,0.f,0.f,0.f,0.f,0.f,0.f,0.f,0.f,0.f,0.f,0.f,0.f,0.f,0.f,0.f})

__device__ __forceinline__ us f2bf(float f) {
  unsigned int u = __float_as_uint(f);
  u += 0x7fffu + ((u >> 16) & 1u);
  return (us)(u >> 16);
}

__device__ __forceinline__ void gload16(const void* g, void* l) {
  __builtin_amdgcn_global_load_lds((const __attribute__((address_space(1))) unsigned int*)g,
                                   (__attribute__((address_space(3))) unsigned int*)l, 16, 0, 0);
}

__device__ __forceinline__ unsigned int cvtpk(float lo, float hi_) {
  unsigned int r;
  asm("v_cvt_pk_bf16_f32 %0, %1, %2" : "=v"(r) : "v"(lo), "v"(hi_));
  return r;
}
__device__ __forceinline__ void plswap(unsigned int& a, unsigned int& b) {
  asm("v_permlane32_swap_b32 %0, %1" : "+v"(a), "+v"(b));
}
__device__ __forceinline__ short8 mkfrag(unsigned int a, unsigned int b, unsigned int c,
                                         unsigned int d) {
  union { unsigned int u[4]; short8 v; } x;
  x.u[0] = a; x.u[1] = b; x.u[2] = c; x.u[3] = d;
  return x.v;
}
// acc (16 f32, rows crow(r,hi)) -> two PV A-fragments (k 0-15, k 16-31)
__device__ __forceinline__ void pack2(const floatx16 p, short8& f0, short8& f1) {
  unsigned int A = cvtpk(p[0], p[1]), B = cvtpk(p[4], p[5]); plswap(A, B);
  unsigned int C = cvtpk(p[2], p[3]), D = cvtpk(p[6], p[7]); plswap(C, D);
  f0 = mkfrag(A, C, B, D);
  unsigned int E = cvtpk(p[8], p[9]), F = cvtpk(p[12], p[13]); plswap(E, F);
  unsigned int G = cvtpk(p[10], p[11]), H = cvtpk(p[14], p[15]); plswap(G, H);
  f1 = mkfrag(E, G, F, H);
}

// ---------------- fp32 -> bf16 bulk convert, all 7 tensors in one launch ----------------
__global__ void k_f2bf_all(const float* q, const float* k, const float* v,
                           const float* wq, const float* wk, const float* wv, const float* wo,
                           us* dq, us* dk, us* dv, us* dwq, us* dwk, us* dwv, us* dwo) {
  const int z = blockIdx.y;
  const float* s; us* d; int n8;
  if (z == 0)      { s = q;  d = dq;  n8 = 524288; }
  else if (z == 1) { s = k;  d = dk;  n8 = 524288; }
  else if (z == 2) { s = v;  d = dv;  n8 = 524288; }
  else if (z == 3) { s = wq; d = dwq; n8 = 131072; }
  else if (z == 4) { s = wk; d = dwk; n8 = 131072; }
  else if (z == 5) { s = wv; d = dwv; n8 = 131072; }
  else             { s = wo; d = dwo; n8 = 131072; }
  int i = blockIdx.x * blockDim.x + threadIdx.x;
  int stride = gridDim.x * blockDim.x;
  for (; i < n8; i += stride) {
    float4 a = ((const float4*)s)[2 * i];
    float4 b = ((const float4*)s)[2 * i + 1];
    union { us u[8]; uint4 vv; } o;
    o.u[0] = f2bf(a.x); o.u[1] = f2bf(a.y); o.u[2] = f2bf(a.z); o.u[3] = f2bf(a.w);
    o.u[4] = f2bf(b.x); o.u[5] = f2bf(b.y); o.u[6] = f2bf(b.z); o.u[7] = f2bf(b.w);
    ((uint4*)d)[i] = o.vv;
  }
}

// ---------------- GEMM: 128x128 tile, BK=32, 4 waves, 4x4 acc, 2-phase LDS dbuf ----------
// MODE 0: bf16 scatter [bh][seq][64]; MODE 1: bf16 -> Vt [bh][64][seq] via LDS transpose;
// MODE 2: fp32 direct.
template <int MODE>
__device__ __forceinline__ void gemm_core(us* pool,
                                          const us* __restrict__ A, const us* __restrict__ B,
                                          const float* __restrict__ bias, void* __restrict__ outp,
                                          int row0, int col0, float scale) {
  // double-buffered tiles: As[b]=[128][32], Bs[b]=[128][32]
  us* const Asb[2] = {pool, pool + 8192};
  us* const Bsb[2] = {pool + 4096, pool + 12288};
  const int t = threadIdx.x;
  const int w = t >> 6, lane = t & 63;
  const int g = lane >> 4, lr = lane & 15;
  const int wm = (w & 1) * 64, wn = (w >> 1) * 64;
  const int srow = lane >> 2, scol = (lane & 3) * 8;
  const int cA = 2 * w;
  const us* Asrc = A + (size_t)(row0 + cA * 16 + srow) * EDIM + scol;
  const us* Bsrc = B + (size_t)(col0 + cA * 16 + srow) * EDIM + scol;

  floatx4 acc[4][4];
#pragma unroll
  for (int mi = 0; mi < 4; ++mi)
#pragma unroll
    for (int ni = 0; ni < 4; ++ni) acc[mi][ni] = (floatx4){0.f, 0.f, 0.f, 0.f};

  // prologue: stage tile 0 into buffer 0
  gload16(Asrc, Asb[0] + cA * 512);
  gload16(Asrc + 16 * EDIM, Asb[0] + cA * 512 + 512);
  gload16(Bsrc, Bsb[0] + cA * 512);
  gload16(Bsrc + 16 * EDIM, Bsb[0] + cA * 512 + 512);
  __syncthreads();

  for (int k0 = 0; k0 < EDIM; k0 += 32) {
    const int cur = (k0 >> 5) & 1;
    if (k0 + 32 < EDIM) {  // issue next-tile loads BEFORE compute (2-phase)
      us* An = Asb[cur ^ 1];
      us* Bn = Bsb[cur ^ 1];
      gload16(Asrc + k0 + 32, An + cA * 512);
      gload16(Asrc + 16 * EDIM + k0 + 32, An + cA * 512 + 512);
      gload16(Bsrc + k0 + 32, Bn + cA * 512);
      gload16(Bsrc + 16 * EDIM + k0 + 32, Bn + cA * 512 + 512);
    }
    const us* Ac = Asb[cur];
    const us* Bc = Bsb[cur];
    short8 af[4], bfr[4];
#pragma unroll
    for (int mi = 0; mi < 4; ++mi) af[mi] = *(const short8*)&Ac[(wm + mi * 16 + lr) * 32 + g * 8];
#pragma unroll
    for (int ni = 0; ni < 4; ++ni) bfr[ni] = *(const short8*)&Bc[(wn + ni * 16 + lr) * 32 + g * 8];
#pragma unroll
    for (int mi = 0; mi < 4; ++mi)
#pragma unroll
      for (int ni = 0; ni < 4; ++ni) acc[mi][ni] = MFMA16(af[mi], bfr[ni], acc[mi][ni]);
    __syncthreads();  // drains vmcnt(0): next tile landed; lgkm: reads of cur done
  }

  if (MODE == 1) {
    us* Ct = pool;  // 128*136 (aliases dbuf; safe after final barrier)
#pragma unroll
    for (int ni = 0; ni < 4; ++ni) {
      const int colloc = wn + ni * 16 + lr;
      const float bv = bias[col0 + colloc];
#pragma unroll
      for (int mi = 0; mi < 4; ++mi) {
        const int b = wm + mi * 16 + 4 * g;
        unsigned int lo = (unsigned int)f2bf(acc[mi][ni][0] + bv) |
                          ((unsigned int)f2bf(acc[mi][ni][2] + bv) << 16);
        unsigned int hi = (unsigned int)f2bf(acc[mi][ni][1] + bv) |
                          ((unsigned int)f2bf(acc[mi][ni][3] + bv) << 16);
        *(unsigned int*)&Ct[colloc * 136 + (b >> 1)] = lo;
        *(unsigned int*)&Ct[colloc * 136 + 64 + (b >> 1)] = hi;
      }
    }
    __syncthreads();
    const int rr = t >> 1, half = t & 1;
    const int c = col0 + rr, h = c >> 6, d = c & 63;
    us* dst = (us*)outp + (((size_t)half * NHEADS + h) * HDIM + d) * LSEQ + (row0 >> 1);
    const us* srcRow = &Ct[rr * 136 + half * 64];
#pragma unroll
    for (int j = 0; j < 8; ++j)
      *(uint4*)(dst + j * 8) = *(const uint4*)(srcRow + j * 8);
  } else {
#pragma unroll
    for (int ni = 0; ni < 4; ++ni) {
      const int col = col0 + wn + ni * 16 + lr;
      const float bv = bias[col];
#pragma unroll
      for (int mi = 0; mi < 4; ++mi) {
#pragma unroll
        for (int i = 0; i < 4; ++i) {
          const int row = row0 + wm + mi * 16 + g * 4 + i;
          const float v = (acc[mi][ni][i] + bv) * scale;
          if (MODE == 2) {
            ((float*)outp)[(size_t)row * EDIM + col] = v;
          } else {
            const int n = row & 1, sq = row >> 1;
            const int h = col >> 6, d = col & 63;
            ((us*)outp)[(((size_t)n * NHEADS + h) * LSEQ + sq) * HDIM + d] = f2bf(v);
          }
        }
      }
    }
  }
}

__global__ __launch_bounds__(256) void k_gemm_qkv(
    const us* __restrict__ Xq, const us* __restrict__ Xk, const us* __restrict__ Xv,
    const us* __restrict__ Wqb, const us* __restrict__ Wkb, const us* __restrict__ Wvb,
    const float* __restrict__ bq, const float* __restrict__ bk, const float* __restrict__ bv,
    us* __restrict__ qo, us* __restrict__ ko, us* __restrict__ vo) {
  __shared__ us pool[17408];
  const int z = blockIdx.z;
  if (z == 0)      gemm_core<0>(pool, Xq, Wqb, bq, qo, blockIdx.x * 128, blockIdx.y * 128, QSCALE);
  else if (z == 1) gemm_core<0>(pool, Xk, Wkb, bk, ko, blockIdx.x * 128, blockIdx.y * 128, 1.0f);
  else             gemm_core<1>(pool, Xv, Wvb, bv, vo, blockIdx.x * 128, blockIdx.y * 128, 1.0f);
}

__global__ __launch_bounds__(256) void k_gemm_o(const us* __restrict__ A, const us* __restrict__ B,
                                                const float* __restrict__ bias, float* __restrict__ out) {
  __shared__ us pool[16384];
  gemm_core<2>(pool, A, B, bias, out, blockIdx.x * 128, blockIdx.y * 128, 1.0f);
}

// ---------------- fused attention (32-row/wave, in-register P), stores 1/ell ----------------
// grid (bh=32, lblk=16), 256 thr. K/V 64x64 dbuf LDS, XOR-swizzled.
__global__ __launch_bounds__(256) void k_attn(const us* __restrict__ qb, const us* __restrict__ kb,
                                              const us* __restrict__ vt, float* __restrict__ rell,
                                              us* __restrict__ O) {
  __shared__ us Ks[2][4096];
  __shared__ us Vs[2][4096];
  __shared__ float elt[4][32];
  const int bh = blockIdx.x;
  const int l0 = blockIdx.y * 128;
  const int t = threadIdx.x, w = t >> 6, lane = t & 63;
  const int ql = lane & 31, hi = lane >> 5;

  // Q in registers: qf[dt] = Q[l0+w*32+ql][dt*16 + hi*8 .. +8]  (B-operand layout)
  short8 qf[4];
  {
    const us* qptr = qb + ((size_t)bh * LSEQ + l0 + w * 32 + ql) * HDIM + hi * 8;
#pragma unroll
    for (int dt = 0; dt < 4; ++dt) qf[dt] = *(const short8*)(qptr + dt * 16);
  }

  // swizzled LDS read offsets (rows ql and 32+ql, chunk (2j+hi)^(row&7))
  int off0[4], off1[4];
#pragma unroll
  for (int j = 0; j < 4; ++j) {
    off0[j] = ql * 64 + (((2 * j + hi) ^ (ql & 7)) << 3);
    off1[j] = (32 + ql) * 64 + (((2 * j + hi) ^ (ql & 7)) << 3);
  }

  const int j0 = 2 * w, j1 = 2 * w + 1;
  const int srA = lane >> 3;
  const int scA = ((lane & 7) ^ (lane >> 3)) * 8;
  const us* Kbase = kb + (size_t)bh * LSEQ * HDIM;
  const us* Vbase = vt + (size_t)bh * HDIM * LSEQ;
  const us* Ksrc0 = Kbase + (j0 * 8 + srA) * HDIM + scA;
  const us* Ksrc1 = Kbase + (j1 * 8 + srA) * HDIM + scA;
  const us* Vsrc0 = Vbase + (size_t)(j0 * 8 + srA) * LSEQ + scA;
  const us* Vsrc1 = Vbase + (size_t)(j1 * 8 + srA) * LSEQ + scA;

  floatx16 oacc0 = ZERO16, oacc1 = ZERO16;
  float ellacc = 0.f;

  gload16(Ksrc0, &Ks[0][j0 * 512]); gload16(Ksrc1, &Ks[0][j1 * 512]);
  gload16(Vsrc0, &Vs[0][j0 * 512]); gload16(Vsrc1, &Vs[0][j1 * 512]);
  __syncthreads();

  for (int it = 0; it < 32; ++it) {
    const int cur = it & 1;
    if (it < 31) {
      const int so = (it + 1) * 64;
      us* Kn = Ks[cur ^ 1]; us* Vn = Vs[cur ^ 1];
      gload16(Ksrc0 + so * HDIM, Kn + j0 * 512);
      gload16(Ksrc1 + so * HDIM, Kn + j1 * 512);
      gload16(Vsrc0 + so, Vn + j0 * 512);
      gload16(Vsrc1 + so, Vn + j1 * 512);
    }
    const us* Kc = Ks[cur];
    const us* Vc = Vs[cur];

    // S^T = K . Q^T : lane holds S[krow crow(r,hi)][qcol ql] for all 64 krows
    floatx16 acc0 = ZERO16, acc1 = ZERO16;
    __builtin_amdgcn_s_setprio(1);
#pragma unroll
    for (int dt = 0; dt < 4; ++dt) {
      acc0 = MFMA32(*(const short8*)&Kc[off0[dt]], qf[dt], acc0);
      acc1 = MFMA32(*(const short8*)&Kc[off1[dt]], qf[dt], acc1);
    }
    __builtin_amdgcn_s_setprio(0);
    // exp2 in place (Q pre-scaled by log2e/8), accumulate ell
#pragma unroll
    for (int r = 0; r < 16; ++r) {
      acc0[r] = __builtin_amdgcn_exp2f(acc0[r]); ellacc += acc0[r];
      acc1[r] = __builtin_amdgcn_exp2f(acc1[r]); ellacc += acc1[r];
    }
    // pack to PV A-fragments (k-slots 0..3 cover s-local 0..63)
    short8 pa0, pa1, pa2, pa3;
    pack2(acc0, pa0, pa1);
    pack2(acc1, pa2, pa3);
    // PV: O[q][d], B-frags from Vt rows d
    __builtin_amdgcn_s_setprio(1);
#pragma unroll
    for (int dt2 = 0; dt2 < 2; ++dt2) {
      floatx16& oa = dt2 ? oacc1 : oacc0;
      const int* off = dt2 ? off1 : off0;
      oa = MFMA32(pa0, *(const short8*)&Vc[off[0]], oa);
      oa = MFMA32(pa1, *(const short8*)&Vc[off[1]], oa);
      oa = MFMA32(pa2, *(const short8*)&Vc[off[2]], oa);
      oa = MFMA32(pa3, *(const short8*)&Vc[off[3]], oa);
    }
    __builtin_amdgcn_s_setprio(0);
    __syncthreads();
  }

  const float elltot = ellacc + __shfl_xor(ellacc, 32);
  if (lane < 32) {
    const float r0 = 1.0f / elltot;
    elt[w][lane] = r0;
    rell[(size_t)bh * LSEQ + l0 + w * 32 + lane] = r0;
  }
  const int n = bh >> 4, hh = bh & 15;
  us* obase = O + (size_t)n * EDIM + (size_t)hh * HDIM;
#pragma unroll
  for (int r = 0; r < 16; ++r) {
    const int q = (r & 3) + 8 * (r >> 2) + 4 * hi;
    const float rl = elt[w][q];
    const size_t l = l0 + w * 32 + q;
    obase[l * (NBATCH * EDIM) + ql] = f2bf(oacc0[r] * rl);
    obase[l * (NBATCH * EDIM) + 32 + ql] = f2bf(oacc1[r] * rl);
  }
}

// ---------------- weights (swapped): W[n][l][s] = mean_h exp2(s*) / ell ----------------
// grid (lblk=8, sblk=32, n=2), QBLK=64/wave. Per-lane 1/ell scalar; K LDS dbuf over heads.
__global__ __launch_bounds__(256, 2) void k_weights(const us* __restrict__ qb, const us* __restrict__ kb,
                                                    const float* __restrict__ rell,
                                                    float* __restrict__ Wout) {
  __shared__ us Ks[2][4096];
  const int l0 = blockIdx.x * 256;
  const int s0 = blockIdx.y * 64;
  const int n = blockIdx.z;
  const int t = threadIdx.x, w = t >> 6, lane = t & 63;
  const int ql = lane & 31, hi = lane >> 5;
  const int lbase = l0 + w * 64;
  const int j0 = 2 * w, j1 = 2 * w + 1;
  const int srA = lane >> 3;
  const int scA = ((lane & 7) ^ (lane >> 3)) * 8;
  const us* Kb0 = kb + ((size_t)(n * NHEADS) * LSEQ + s0 + j0 * 8 + srA) * HDIM + scA;
  const us* Kb1 = kb + ((size_t)(n * NHEADS) * LSEQ + s0 + j1 * 8 + srA) * HDIM + scA;

  int off0[4], off1[4];
#pragma unroll
  for (int j = 0; j < 4; ++j) {
    off0[j] = ql * 64 + (((2 * j + hi) ^ (ql & 7)) << 3);
    off1[j] = (32 + ql) * 64 + (((2 * j + hi) ^ (ql & 7)) << 3);
  }

  floatx16 wa00 = ZERO16, wa01 = ZERO16, wa10 = ZERO16, wa11 = ZERO16;

  gload16(Kb0, &Ks[0][j0 * 512]); gload16(Kb1, &Ks[0][j1 * 512]);

  // current-head Q fragments + 1/ell (per-lane scalars)
  short8 qc0[4], qc1[4];
  float rlc0, rlc1;
  {
    const us* qp0 = qb + ((size_t)(n * NHEADS) * LSEQ + lbase + ql) * HDIM + hi * 8;
    const us* qp1 = qp0 + 32 * HDIM;
#pragma unroll
    for (int dt = 0; dt < 4; ++dt) {
      qc0[dt] = *(const short8*)(qp0 + dt * 16);
      qc1[dt] = *(const short8*)(qp1 + dt * 16);
    }
    rlc0 = rell[(size_t)(n * NHEADS) * LSEQ + lbase + ql];
    rlc1 = rell[(size_t)(n * NHEADS) * LSEQ + lbase + 32 + ql];
  }
  __syncthreads();

  for (int h = 0; h < NHEADS; ++h) {
    const int cur = h & 1;
    short8 qn0[4], qn1[4];
    float rln0 = 0.f, rln1 = 0.f;
    if (h < NHEADS - 1) {
      us* Kn2 = Ks[cur ^ 1];
      gload16(Kb0 + (size_t)(h + 1) * LSEQ * HDIM, Kn2 + j0 * 512);
      gload16(Kb1 + (size_t)(h + 1) * LSEQ * HDIM, Kn2 + j1 * 512);
      const us* qp0 = qb + ((size_t)(n * NHEADS + h + 1) * LSEQ + lbase + ql) * HDIM + hi * 8;
      const us* qp1 = qp0 + 32 * HDIM;
#pragma unroll
      for (int dt = 0; dt < 4; ++dt) {
        qn0[dt] = *(const short8*)(qp0 + dt * 16);
        qn1[dt] = *(const short8*)(qp1 + dt * 16);
      }
      rln0 = rell[(size_t)(n * NHEADS + h + 1) * LSEQ + lbase + ql];
      rln1 = rell[(size_t)(n * NHEADS + h + 1) * LSEQ + lbase + 32 + ql];
    }
    const us* Kc = Ks[cur];
    short8 kf0[4], kf1[4];
#pragma unroll
    for (int dt = 0; dt < 4; ++dt) {
      kf0[dt] = *(const short8*)&Kc[off0[dt]];
      kf1[dt] = *(const short8*)&Kc[off1[dt]];
    }
    {
      floatx16 aA = ZERO16, aB = ZERO16;
#pragma unroll
      for (int dt = 0; dt < 4; ++dt) {
        aA = MFMA32(kf0[dt], qc0[dt], aA);
        aB = MFMA32(kf1[dt], qc0[dt], aB);
      }
#pragma unroll
      for (int r = 0; r < 16; ++r) {
        wa00[r] += __builtin_amdgcn_exp2f(aA[r]) * rlc0;
        wa01[r] += __builtin_amdgcn_exp2f(aB[r]) * rlc0;
      }
    }
    {
      floatx16 cA = ZERO16, cB = ZERO16;
#pragma unroll
      for (int dt = 0; dt < 4; ++dt) {
        cA = MFMA32(kf0[dt], qc1[dt], cA);
        cB = MFMA32(kf1[dt], qc1[dt], cB);
      }
#pragma unroll
      for (int r = 0; r < 16; ++r) {
        wa10[r] += __builtin_amdgcn_exp2f(cA[r]) * rlc1;
        wa11[r] += __builtin_amdgcn_exp2f(cB[r]) * rlc1;
      }
    }
#pragma unroll
    for (int dt = 0; dt < 4; ++dt) { qc0[dt] = qn0[dt]; qc1[dt] = qn1[dt]; }
    rlc0 = rln0; rlc1 = rln1;
    __syncthreads();
  }

  // write: lane owns rows q = lbase + qh*32 + ql; cols s = s0 + sh*32 + crow(r,hi)
  float* wb0 = Wout + (size_t)n * LSEQ * LSEQ + (size_t)(lbase + ql) * LSEQ + s0;
  float* wb1 = Wout + (size_t)n * LSEQ * LSEQ + (size_t)(lbase + 32 + ql) * LSEQ + s0;
#pragma unroll
  for (int r = 0; r < 16; ++r) {
    const int cr = (r & 3) + 8 * (r >> 2) + 4 * hi;
    wb0[cr] = wa00[r] * 0.0625f;
    wb0[32 + cr] = wa01[r] * 0.0625f;
    wb1[cr] = wa10[r] * 0.0625f;
    wb1[32 + cr] = wa11[r] * 0.0625f;
  }
}

extern "C" void kernel_launch(void* const* d_in, const int* in_sizes, int n_in,
                              void* d_out, int out_size, void* d_ws, size_t ws_size,
                              hipStream_t stream) {
  const float* query = (const float*)d_in[0];
  const float* key   = (const float*)d_in[1];
  const float* value = (const float*)d_in[2];
  const float* Wq = (const float*)d_in[3]; const float* bq = (const float*)d_in[4];
  const float* Wk = (const float*)d_in[5]; const float* bk = (const float*)d_in[6];
  const float* Wv = (const float*)d_in[7]; const float* bv = (const float*)d_in[8];
  const float* Wo = (const float*)d_in[9]; const float* bo = (const float*)d_in[10];

  const size_t MB = 1u << 20;
  char* ws = (char*)d_ws;
  us* Xq  = (us*)(ws + 0 * MB);
  us* Xk  = (us*)(ws + 8 * MB);
  us* Xv  = (us*)(ws + 16 * MB);
  us* Wqb = (us*)(ws + 24 * MB);
  us* Wkb = (us*)(ws + 26 * MB);
  us* Wvb = (us*)(ws + 28 * MB);
  us* Wob = (us*)(ws + 30 * MB);
  us* qbuf = (us*)(ws + 32 * MB);
  us* kbuf = (us*)(ws + 40 * MB);
  us* Vt   = (us*)(ws + 48 * MB);
  us* Obuf = (us*)(ws + 56 * MB);
  float* rell = (float*)(ws + 64 * MB);

  k_f2bf_all<<<dim3(256, 7), 256, 0, stream>>>(query, key, value, Wq, Wk, Wv, Wo,
                                               Xq, Xk, Xv, Wqb, Wkb, Wvb, Wob);

  k_gemm_qkv<<<dim3(32, 8, 3), 256, 0, stream>>>(Xq, Xk, Xv, Wqb, Wkb, Wvb, bq, bk, bv,
                                                 qbuf, kbuf, Vt);

  k_attn<<<dim3(32, 16), 256, 0, stream>>>(qbuf, kbuf, Vt, rell, Obuf);

  k_gemm_o<<<dim3(32, 8), 256, 0, stream>>>(Obuf, Wob, bo, (float*)d_out);
  k_weights<<<dim3(8, 32, 2), 256, 0, stream>>>(qbuf, kbuf, rell, (float*)d_out + 4194304);
}

// Round 8
// 156.726 us; speedup vs baseline: 3.9546x; 1.0947x over previous
//
#include <hip/hip_runtime.h>

#define EDIM 1024
#define LSEQ 2048
#define NBATCH 2
#define NHEADS 16
#define HDIM 64
#define QSCALE 0.18033688011112042f  // log2(e)/8: exp(s/8) == exp2(s*QSCALE)

typedef unsigned short us;
typedef __attribute__((ext_vector_type(8))) short short8;
typedef __attribute__((ext_vector_type(4))) float floatx4;
typedef __attribute__((ext_vector_type(16))) float floatx16;

#define MFMA16(a, b, c) __builtin_amdgcn_mfma_f32_16x16x32_bf16((a), (b), (c), 0, 0, 0)
#define MFMA32(a, b, c) __builtin_amdgcn_mfma_f32_32x32x16_bf16((a), (b), (c), 0, 0, 0)
#define ZERO16 ((floatx16){0.f,0.f,0.f,0.f,0.f,0.f,0.f,0.f,0.f,0.f,0.f,0.f,0.f,0.f,0.f,0.f})

#define WAIT_VM4 asm volatile("s_waitcnt vmcnt(4)" ::: "memory")
#define WAIT_VM0 asm volatile("s_waitcnt vmcnt(0)" ::: "memory")
#define WAIT_LGKM0 asm volatile("s_waitcnt lgkmcnt(0)" ::: "memory")
#define CFENCE asm volatile("" ::: "memory")

__device__ __forceinline__ us f2bf(float f) {
  unsigned int u = __float_as_uint(f);
  u += 0x7fffu + ((u >> 16) & 1u);
  return (us)(u >> 16);
}

__device__ __forceinline__ void gload16(const void* g, void* l) {
  __builtin_amdgcn_global_load_lds((const __attribute__((address_space(1))) unsigned int*)g,
                                   (__attribute__((address_space(3))) unsigned int*)l, 16, 0, 0);
}

__device__ __forceinline__ unsigned int cvtpk(float lo, float hi_) {
  unsigned int r;
  asm("v_cvt_pk_bf16_f32 %0, %1, %2" : "=v"(r) : "v"(lo), "v"(hi_));
  return r;
}
__device__ __forceinline__ void plswap(unsigned int& a, unsigned int& b) {
  asm("v_permlane32_swap_b32 %0, %1" : "+v"(a), "+v"(b));
}
__device__ __forceinline__ short8 mkfrag(unsigned int a, unsigned int b, unsigned int c,
                                         unsigned int d) {
  union { unsigned int u[4]; short8 v; } x;
  x.u[0] = a; x.u[1] = b; x.u[2] = c; x.u[3] = d;
  return x.v;
}
// acc (16 f32, rows crow(r,hi)) -> two PV A-fragments (k 0-15, k 16-31)
__device__ __forceinline__ void pack2(const floatx16 p, short8& f0, short8& f1) {
  unsigned int A = cvtpk(p[0], p[1]), B = cvtpk(p[4], p[5]); plswap(A, B);
  unsigned int C = cvtpk(p[2], p[3]), D = cvtpk(p[6], p[7]); plswap(C, D);
  f0 = mkfrag(A, C, B, D);
  unsigned int E = cvtpk(p[8], p[9]), F = cvtpk(p[12], p[13]); plswap(E, F);
  unsigned int G = cvtpk(p[10], p[11]), H = cvtpk(p[14], p[15]); plswap(G, H);
  f1 = mkfrag(E, G, F, H);
}

// ---------------- fp32 -> bf16 bulk convert, all 7 tensors in one launch ----------------
__global__ void k_f2bf_all(const float* q, const float* k, const float* v,
                           const float* wq, const float* wk, const float* wv, const float* wo,
                           us* dq, us* dk, us* dv, us* dwq, us* dwk, us* dwv, us* dwo) {
  const int z = blockIdx.y;
  const float* s; us* d; int n8;
  if (z == 0)      { s = q;  d = dq;  n8 = 524288; }
  else if (z == 1) { s = k;  d = dk;  n8 = 524288; }
  else if (z == 2) { s = v;  d = dv;  n8 = 524288; }
  else if (z == 3) { s = wq; d = dwq; n8 = 131072; }
  else if (z == 4) { s = wk; d = dwk; n8 = 131072; }
  else if (z == 5) { s = wv; d = dwv; n8 = 131072; }
  else             { s = wo; d = dwo; n8 = 131072; }
  int i = blockIdx.x * blockDim.x + threadIdx.x;
  int stride = gridDim.x * blockDim.x;
  for (; i < n8; i += stride) {
    float4 a = ((const float4*)s)[2 * i];
    float4 b = ((const float4*)s)[2 * i + 1];
    union { us u[8]; uint4 vv; } o;
    o.u[0] = f2bf(a.x); o.u[1] = f2bf(a.y); o.u[2] = f2bf(a.z); o.u[3] = f2bf(a.w);
    o.u[4] = f2bf(b.x); o.u[5] = f2bf(b.y); o.u[6] = f2bf(b.z); o.u[7] = f2bf(b.w);
    ((uint4*)d)[i] = o.vv;
  }
}

// ------- GEMM: 128x128 tile, BK=32, 4 waves, 4x4 acc, counted-vmcnt depth-2 pipeline -------
// MODE 0: bf16 scatter [bh][seq][64]; MODE 1: bf16 -> Vt [bh][64][seq] via LDS transpose;
// MODE 2: fp32 direct.
template <int MODE>
__device__ __forceinline__ void gemm_core(us* pool,
                                          const us* __restrict__ A, const us* __restrict__ B,
                                          const float* __restrict__ bias, void* __restrict__ outp,
                                          int row0, int col0, float scale) {
  // double-buffered tiles: As[b]=[128][32], Bs[b]=[128][32]
  us* const Asb[2] = {pool, pool + 8192};
  us* const Bsb[2] = {pool + 4096, pool + 12288};
  const int t = threadIdx.x;
  const int w = t >> 6, lane = t & 63;
  const int g = lane >> 4, lr = lane & 15;
  const int wm = (w & 1) * 64, wn = (w >> 1) * 64;
  const int srow = lane >> 2, scol = (lane & 3) * 8;
  const int cA = 2 * w;
  const us* Asrc = A + (size_t)(row0 + cA * 16 + srow) * EDIM + scol;
  const us* Bsrc = B + (size_t)(col0 + cA * 16 + srow) * EDIM + scol;

  floatx4 acc[4][4];
#pragma unroll
  for (int mi = 0; mi < 4; ++mi)
#pragma unroll
    for (int ni = 0; ni < 4; ++ni) acc[mi][ni] = (floatx4){0.f, 0.f, 0.f, 0.f};

  // per wave per tile: 4 VMEM ops (2 A-chunks + 2 B-chunks)
  auto stage = [&](int kt, int b) {
    const int k0 = kt * 32;
    gload16(Asrc + k0, Asb[b] + cA * 512);
    gload16(Asrc + 16 * EDIM + k0, Asb[b] + cA * 512 + 512);
    gload16(Bsrc + k0, Bsb[b] + cA * 512);
    gload16(Bsrc + 16 * EDIM + k0, Bsb[b] + cA * 512 + 512);
  };

  stage(0, 0);
  stage(1, 1);  // 8 VMEM/wave in flight

  for (int kt = 0; kt < 32; ++kt) {
    if (kt < 31) { WAIT_VM4; } else { WAIT_VM0; }  // own tile-kt loads landed; keep t+1 in flight
    __builtin_amdgcn_s_barrier();                  // collective: tile kt fully resident
    CFENCE;
    const us* Ac = Asb[kt & 1];
    const us* Bc = Bsb[kt & 1];
    short8 af[4], bfr[4];
#pragma unroll
    for (int mi = 0; mi < 4; ++mi) af[mi] = *(const short8*)&Ac[(wm + mi * 16 + lr) * 32 + g * 8];
#pragma unroll
    for (int ni = 0; ni < 4; ++ni) bfr[ni] = *(const short8*)&Bc[(wn + ni * 16 + lr) * 32 + g * 8];
#pragma unroll
    for (int mi = 0; mi < 4; ++mi)
#pragma unroll
      for (int ni = 0; ni < 4; ++ni) acc[mi][ni] = MFMA16(af[mi], bfr[ni], acc[mi][ni]);
    WAIT_LGKM0;                                    // my ds_reads retired (data in regs)
    __builtin_amdgcn_s_barrier();                  // collective: buf[kt&1] reusable
    CFENCE;
    if (kt + 2 < 32) stage(kt + 2, kt & 1);
  }

  if (MODE == 1) {
    us* Ct = pool;  // 128*136 (aliases dbuf; safe: vmcnt drained, all reads done)
#pragma unroll
    for (int ni = 0; ni < 4; ++ni) {
      const int colloc = wn + ni * 16 + lr;
      const float bv = bias[col0 + colloc];
#pragma unroll
      for (int mi = 0; mi < 4; ++mi) {
        const int b = wm + mi * 16 + 4 * g;
        unsigned int lo = (unsigned int)f2bf(acc[mi][ni][0] + bv) |
                          ((unsigned int)f2bf(acc[mi][ni][2] + bv) << 16);
        unsigned int hi = (unsigned int)f2bf(acc[mi][ni][1] + bv) |
                          ((unsigned int)f2bf(acc[mi][ni][3] + bv) << 16);
        *(unsigned int*)&Ct[colloc * 136 + (b >> 1)] = lo;
        *(unsigned int*)&Ct[colloc * 136 + 64 + (b >> 1)] = hi;
      }
    }
    __syncthreads();
    const int rr = t >> 1, half = t & 1;
    const int c = col0 + rr, h = c >> 6, d = c & 63;
    us* dst = (us*)outp + (((size_t)half * NHEADS + h) * HDIM + d) * LSEQ + (row0 >> 1);
    const us* srcRow = &Ct[rr * 136 + half * 64];
#pragma unroll
    for (int j = 0; j < 8; ++j)
      *(uint4*)(dst + j * 8) = *(const uint4*)(srcRow + j * 8);
  } else {
#pragma unroll
    for (int ni = 0; ni < 4; ++ni) {
      const int col = col0 + wn + ni * 16 + lr;
      const float bv = bias[col];
#pragma unroll
      for (int mi = 0; mi < 4; ++mi) {
#pragma unroll
        for (int i = 0; i < 4; ++i) {
          const int row = row0 + wm + mi * 16 + g * 4 + i;
          const float v = (acc[mi][ni][i] + bv) * scale;
          if (MODE == 2) {
            ((float*)outp)[(size_t)row * EDIM + col] = v;
          } else {
            const int n = row & 1, sq = row >> 1;
            const int h = col >> 6, d = col & 63;
            ((us*)outp)[(((size_t)n * NHEADS + h) * LSEQ + sq) * HDIM + d] = f2bf(v);
          }
        }
      }
    }
  }
}

__global__ __launch_bounds__(256) void k_gemm_qkv(
    const us* __restrict__ Xq, const us* __restrict__ Xk, const us* __restrict__ Xv,
    const us* __restrict__ Wqb, const us* __restrict__ Wkb, const us* __restrict__ Wvb,
    const float* __restrict__ bq, const float* __restrict__ bk, const float* __restrict__ bv,
    us* __restrict__ qo, us* __restrict__ ko, us* __restrict__ vo) {
  __shared__ us pool[17408];
  const int z = blockIdx.z;
  if (z == 0)      gemm_core<0>(pool, Xq, Wqb, bq, qo, blockIdx.x * 128, blockIdx.y * 128, QSCALE);
  else if (z == 1) gemm_core<0>(pool, Xk, Wkb, bk, ko, blockIdx.x * 128, blockIdx.y * 128, 1.0f);
  else             gemm_core<1>(pool, Xv, Wvb, bv, vo, blockIdx.x * 128, blockIdx.y * 128, 1.0f);
}

__global__ __launch_bounds__(256) void k_gemm_o(const us* __restrict__ A, const us* __restrict__ B,
                                                const float* __restrict__ bias, float* __restrict__ out) {
  __shared__ us pool[16384];
  gemm_core<2>(pool, A, B, bias, out, blockIdx.x * 128, blockIdx.y * 128, 1.0f);
}

// ------- fused attention (32-row/wave, in-register P), counted-vmcnt depth-2, stores 1/ell ----
// grid (bh=32, lblk=16), 256 thr. K/V 64x64 dbuf LDS, XOR-swizzled.
__global__ __launch_bounds__(256) void k_attn(const us* __restrict__ qb, const us* __restrict__ kb,
                                              const us* __restrict__ vt, float* __restrict__ rell,
                                              us* __restrict__ O) {
  __shared__ us Ks[2][4096];
  __shared__ us Vs[2][4096];
  __shared__ float elt[4][32];
  const int bh = blockIdx.x;
  const int l0 = blockIdx.y * 128;
  const int t = threadIdx.x, w = t >> 6, lane = t & 63;
  const int ql = lane & 31, hi = lane >> 5;

  // Q in registers: qf[dt] = Q[l0+w*32+ql][dt*16 + hi*8 .. +8]  (B-operand layout)
  short8 qf[4];
  {
    const us* qptr = qb + ((size_t)bh * LSEQ + l0 + w * 32 + ql) * HDIM + hi * 8;
#pragma unroll
    for (int dt = 0; dt < 4; ++dt) qf[dt] = *(const short8*)(qptr + dt * 16);
  }

  // swizzled LDS read offsets (rows ql and 32+ql, chunk (2j+hi)^(row&7))
  int off0[4], off1[4];
#pragma unroll
  for (int j = 0; j < 4; ++j) {
    off0[j] = ql * 64 + (((2 * j + hi) ^ (ql & 7)) << 3);
    off1[j] = (32 + ql) * 64 + (((2 * j + hi) ^ (ql & 7)) << 3);
  }

  const int j0 = 2 * w, j1 = 2 * w + 1;
  const int srA = lane >> 3;
  const int scA = ((lane & 7) ^ (lane >> 3)) * 8;
  const us* Kbase = kb + (size_t)bh * LSEQ * HDIM;
  const us* Vbase = vt + (size_t)bh * HDIM * LSEQ;
  const us* Ksrc0 = Kbase + (j0 * 8 + srA) * HDIM + scA;
  const us* Ksrc1 = Kbase + (j1 * 8 + srA) * HDIM + scA;
  const us* Vsrc0 = Vbase + (size_t)(j0 * 8 + srA) * LSEQ + scA;
  const us* Vsrc1 = Vbase + (size_t)(j1 * 8 + srA) * LSEQ + scA;

  floatx16 oacc0 = ZERO16, oacc1 = ZERO16;
  float ellacc = 0.f;

  // per wave per tile: 4 VMEM ops (2 K + 2 V)
  auto stageKV = [&](int kt, int b) {
    const int so = kt * 64;
    gload16(Ksrc0 + so * HDIM, &Ks[b][j0 * 512]);
    gload16(Ksrc1 + so * HDIM, &Ks[b][j1 * 512]);
    gload16(Vsrc0 + so, &Vs[b][j0 * 512]);
    gload16(Vsrc1 + so, &Vs[b][j1 * 512]);
  };

  stageKV(0, 0);
  stageKV(1, 1);  // 8 VMEM/wave in flight

  for (int it = 0; it < 32; ++it) {
    if (it < 31) { WAIT_VM4; } else { WAIT_VM0; }
    __builtin_amdgcn_s_barrier();  // collective: tile it resident
    CFENCE;
    const us* Kc = Ks[it & 1];
    const us* Vc = Vs[it & 1];

    // S^T = K . Q^T : lane holds S[krow crow(r,hi)][qcol ql] for all 64 krows
    floatx16 acc0 = ZERO16, acc1 = ZERO16;
    __builtin_amdgcn_s_setprio(1);
#pragma unroll
    for (int dt = 0; dt < 4; ++dt) {
      acc0 = MFMA32(*(const short8*)&Kc[off0[dt]], qf[dt], acc0);
      acc1 = MFMA32(*(const short8*)&Kc[off1[dt]], qf[dt], acc1);
    }
    __builtin_amdgcn_s_setprio(0);
    // exp2 in place (Q pre-scaled by log2e/8), accumulate ell
#pragma unroll
    for (int r = 0; r < 16; ++r) {
      acc0[r] = __builtin_amdgcn_exp2f(acc0[r]); ellacc += acc0[r];
      acc1[r] = __builtin_amdgcn_exp2f(acc1[r]); ellacc += acc1[r];
    }
    // pack to PV A-fragments (k-slots 0..3 cover s-local 0..63)
    short8 pa0, pa1, pa2, pa3;
    pack2(acc0, pa0, pa1);
    pack2(acc1, pa2, pa3);
    // PV: O[q][d], B-frags from Vt rows d
    __builtin_amdgcn_s_setprio(1);
#pragma unroll
    for (int dt2 = 0; dt2 < 2; ++dt2) {
      floatx16& oa = dt2 ? oacc1 : oacc0;
      const int* off = dt2 ? off1 : off0;
      oa = MFMA32(pa0, *(const short8*)&Vc[off[0]], oa);
      oa = MFMA32(pa1, *(const short8*)&Vc[off[1]], oa);
      oa = MFMA32(pa2, *(const short8*)&Vc[off[2]], oa);
      oa = MFMA32(pa3, *(const short8*)&Vc[off[3]], oa);
    }
    __builtin_amdgcn_s_setprio(0);
    WAIT_LGKM0;                    // my K/V ds_reads retired
    __builtin_amdgcn_s_barrier();  // collective: buf[it&1] reusable
    CFENCE;
    if (it + 2 < 32) stageKV(it + 2, it & 1);
  }

  const float elltot = ellacc + __shfl_xor(ellacc, 32);
  if (lane < 32) {
    const float r0 = 1.0f / elltot;
    elt[w][lane] = r0;
    rell[(size_t)bh * LSEQ + l0 + w * 32 + lane] = r0;
  }
  const int n = bh >> 4, hh = bh & 15;
  us* obase = O + (size_t)n * EDIM + (size_t)hh * HDIM;
#pragma unroll
  for (int r = 0; r < 16; ++r) {
    const int q = (r & 3) + 8 * (r >> 2) + 4 * hi;
    const float rl = elt[w][q];
    const size_t l = l0 + w * 32 + q;
    obase[l * (NBATCH * EDIM) + ql] = f2bf(oacc0[r] * rl);
    obase[l * (NBATCH * EDIM) + 32 + ql] = f2bf(oacc1[r] * rl);
  }
}

// ---------------- weights (swapped): W[n][l][s] = mean_h exp2(s*) / ell ----------------
// grid (lblk=8, sblk=32, n=2), QBLK=64/wave. Per-lane 1/ell scalar; K LDS dbuf over heads.
__global__ __launch_bounds__(256, 2) void k_weights(const us* __restrict__ qb, const us* __restrict__ kb,
                                                    const float* __restrict__ rell,
                                                    float* __restrict__ Wout) {
  __shared__ us Ks[2][4096];
  const int l0 = blockIdx.x * 256;
  const int s0 = blockIdx.y * 64;
  const int n = blockIdx.z;
  const int t = threadIdx.x, w = t >> 6, lane = t & 63;
  const int ql = lane & 31, hi = lane >> 5;
  const int lbase = l0 + w * 64;
  const int j0 = 2 * w, j1 = 2 * w + 1;
  const int srA = lane >> 3;
  const int scA = ((lane & 7) ^ (lane >> 3)) * 8;
  const us* Kb0 = kb + ((size_t)(n * NHEADS) * LSEQ + s0 + j0 * 8 + srA) * HDIM + scA;
  const us* Kb1 = kb + ((size_t)(n * NHEADS) * LSEQ + s0 + j1 * 8 + srA) * HDIM + scA;

  int off0[4], off1[4];
#pragma unroll
  for (int j = 0; j < 4; ++j) {
    off0[j] = ql * 64 + (((2 * j + hi) ^ (ql & 7)) << 3);
    off1[j] = (32 + ql) * 64 + (((2 * j + hi) ^ (ql & 7)) << 3);
  }

  floatx16 wa00 = ZERO16, wa01 = ZERO16, wa10 = ZERO16, wa11 = ZERO16;

  gload16(Kb0, &Ks[0][j0 * 512]); gload16(Kb1, &Ks[0][j1 * 512]);

  // current-head Q fragments + 1/ell (per-lane scalars)
  short8 qc0[4], qc1[4];
  float rlc0, rlc1;
  {
    const us* qp0 = qb + ((size_t)(n * NHEADS) * LSEQ + lbase + ql) * HDIM + hi * 8;
    const us* qp1 = qp0 + 32 * HDIM;
#pragma unroll
    for (int dt = 0; dt < 4; ++dt) {
      qc0[dt] = *(const short8*)(qp0 + dt * 16);
      qc1[dt] = *(const short8*)(qp1 + dt * 16);
    }
    rlc0 = rell[(size_t)(n * NHEADS) * LSEQ + lbase + ql];
    rlc1 = rell[(size_t)(n * NHEADS) * LSEQ + lbase + 32 + ql];
  }
  __syncthreads();

  for (int h = 0; h < NHEADS; ++h) {
    const int cur = h & 1;
    short8 qn0[4], qn1[4];
    float rln0 = 0.f, rln1 = 0.f;
    if (h < NHEADS - 1) {
      us* Kn2 = Ks[cur ^ 1];
      gload16(Kb0 + (size_t)(h + 1) * LSEQ * HDIM, Kn2 + j0 * 512);
      gload16(Kb1 + (size_t)(h + 1) * LSEQ * HDIM, Kn2 + j1 * 512);
      const us* qp0 = qb + ((size_t)(n * NHEADS + h + 1) * LSEQ + lbase + ql) * HDIM + hi * 8;
      const us* qp1 = qp0 + 32 * HDIM;
#pragma unroll
      for (int dt = 0; dt < 4; ++dt) {
        qn0[dt] = *(const short8*)(qp0 + dt * 16);
        qn1[dt] = *(const short8*)(qp1 + dt * 16);
      }
      rln0 = rell[(size_t)(n * NHEADS + h + 1) * LSEQ + lbase + ql];
      rln1 = rell[(size_t)(n * NHEADS + h + 1) * LSEQ + lbase + 32 + ql];
    }
    const us* Kc = Ks[cur];
    short8 kf0[4], kf1[4];
#pragma unroll
    for (int dt = 0; dt < 4; ++dt) {
      kf0[dt] = *(const short8*)&Kc[off0[dt]];
      kf1[dt] = *(const short8*)&Kc[off1[dt]];
    }
    {
      floatx16 aA = ZERO16, aB = ZERO16;
#pragma unroll
      for (int dt = 0; dt < 4; ++dt) {
        aA = MFMA32(kf0[dt], qc0[dt], aA);
        aB = MFMA32(kf1[dt], qc0[dt], aB);
      }
#pragma unroll
      for (int r = 0; r < 16; ++r) {
        wa00[r] += __builtin_amdgcn_exp2f(aA[r]) * rlc0;
        wa01[r] += __builtin_amdgcn_exp2f(aB[r]) * rlc0;
      }
    }
    {
      floatx16 cA = ZERO16, cB = ZERO16;
#pragma unroll
      for (int dt = 0; dt < 4; ++dt) {
        cA = MFMA32(kf0[dt], qc1[dt], cA);
        cB = MFMA32(kf1[dt], qc1[dt], cB);
      }
#pragma unroll
      for (int r = 0; r < 16; ++r) {
        wa10[r] += __builtin_amdgcn_exp2f(cA[r]) * rlc1;
        wa11[r] += __builtin_amdgcn_exp2f(cB[r]) * rlc1;
      }
    }
#pragma unroll
    for (int dt = 0; dt < 4; ++dt) { qc0[dt] = qn0[dt]; qc1[dt] = qn1[dt]; }
    rlc0 = rln0; rlc1 = rln1;
    __syncthreads();
  }

  // write: lane owns rows q = lbase + qh*32 + ql; cols s = s0 + sh*32 + crow(r,hi)
  float* wb0 = Wout + (size_t)n * LSEQ * LSEQ + (size_t)(lbase + ql) * LSEQ + s0;
  float* wb1 = Wout + (size_t)n * LSEQ * LSEQ + (size_t)(lbase + 32 + ql) * LSEQ + s0;
#pragma unroll
  for (int r = 0; r < 16; ++r) {
    const int cr = (r & 3) + 8 * (r >> 2) + 4 * hi;
    wb0[cr] = wa00[r] * 0.0625f;
    wb0[32 + cr] = wa01[r] * 0.0625f;
    wb1[cr] = wa10[r] * 0.0625f;
    wb1[32 + cr] = wa11[r] * 0.0625f;
  }
}

extern "C" void kernel_launch(void* const* d_in, const int* in_sizes, int n_in,
                              void* d_out, int out_size, void* d_ws, size_t ws_size,
                              hipStream_t stream) {
  const float* query = (const float*)d_in[0];
  const float* key   = (const float*)d_in[1];
  const float* value = (const float*)d_in[2];
  const float* Wq = (const float*)d_in[3]; const float* bq = (const float*)d_in[4];
  const float* Wk = (const float*)d_in[5]; const float* bk = (const float*)d_in[6];
  const float* Wv = (const float*)d_in[7]; const float* bv = (const float*)d_in[8];
  const float* Wo = (const float*)d_in[9]; const float* bo = (const float*)d_in[10];

  const size_t MB = 1u << 20;
  char* ws = (char*)d_ws;
  us* Xq  = (us*)(ws + 0 * MB);
  us* Xk  = (us*)(ws + 8 * MB);
  us* Xv  = (us*)(ws + 16 * MB);
  us* Wqb = (us*)(ws + 24 * MB);
  us* Wkb = (us*)(ws + 26 * MB);
  us* Wvb = (us*)(ws + 28 * MB);
  us* Wob = (us*)(ws + 30 * MB);
  us* qbuf = (us*)(ws + 32 * MB);
  us* kbuf = (us*)(ws + 40 * MB);
  us* Vt   = (us*)(ws + 48 * MB);
  us* Obuf = (us*)(ws + 56 * MB);
  float* rell = (float*)(ws + 64 * MB);

  k_f2bf_all<<<dim3(256, 7), 256, 0, stream>>>(query, key, value, Wq, Wk, Wv, Wo,
                                               Xq, Xk, Xv, Wqb, Wkb, Wvb, Wob);

  k_gemm_qkv<<<dim3(32, 8, 3), 256, 0, stream>>>(Xq, Xk, Xv, Wqb, Wkb, Wvb, bq, bk, bv,
                                                 qbuf, kbuf, Vt);

  k_attn<<<dim3(32, 16), 256, 0, stream>>>(qbuf, kbuf, Vt, rell, Obuf);

  k_gemm_o<<<dim3(32, 8), 256, 0, stream>>>(Obuf, Wob, bo, (float*)d_out);
  k_weights<<<dim3(8, 32, 2), 256, 0, stream>>>(qbuf, kbuf, rell, (float*)d_out + 4194304);
}